// Round 1
// baseline (639.360 us; speedup 1.0000x reference)
//
#include <hip/hip_runtime.h>
#include <hip/hip_bf16.h>
#include <stdint.h>

// Problem dims
#define M_DIM 4096      // 2*2048 rows of x
#define K_DIM 4096
#define N_DIM 11008
#define KP    2048      // K/2 packed int32 per w row

// GEMM tiling (m97 structure: 128x128 tile, BK=64, 4 waves, 4x4 frags/wave)
#define BM 128
#define BN 128
#define BK 64
#define NTM (M_DIM/BM)          // 32
#define NTN (N_DIM/BN)          // 86
#define NBLK (NTM*NTN)          // 2752

typedef __attribute__((ext_vector_type(8))) short  bf16x8;
typedef __attribute__((ext_vector_type(4))) float  f32x4;
typedef __attribute__((ext_vector_type(8))) unsigned short u16x8;

typedef const void __attribute__((address_space(1)))* gas_ptr;
typedef void __attribute__((address_space(3)))* las_ptr;

__device__ __forceinline__ void async_copy16(void* lds, const void* g) {
  // width=16 global->LDS DMA; LDS dest is wave-uniform base + lane*16
  __builtin_amdgcn_global_load_lds((gas_ptr)g, (las_ptr)lds, 16, 0, 0);
}

__device__ __forceinline__ unsigned short f2bf_rne(float f) {
  uint32_t u = __builtin_bit_cast(uint32_t, f);
  u += 0x7FFFu + ((u >> 16) & 1u);
  return (unsigned short)(u >> 16);
}
// exact small-int -> bf16 (ints in [-8,7] are exact; truncation == exact)
__device__ __forceinline__ unsigned short i2bf(int v) {
  float f = (float)v;
  return (unsigned short)(__builtin_bit_cast(uint32_t, f) >> 16);
}
// extract signed int4: which=0 -> low nibble, which=1 -> high nibble
__device__ __forceinline__ int sx4(int b, int which) {
  return ((int)((uint32_t)b << (28 - 4 * which))) >> 28;
}

// ---------------- pre-pass kernels ----------------

__global__ __launch_bounds__(256) void cvt_x_kernel(const float* __restrict__ x,
                                                    unsigned short* __restrict__ xb) {
  const int n4 = M_DIM * K_DIM / 4;
  int i = blockIdx.x * blockDim.x + threadIdx.x;
  const int stride = gridDim.x * blockDim.x;
  for (; i < n4; i += stride) {
    float4 v = ((const float4*)x)[i];
    ushort4 r;
    r.x = f2bf_rne(v.x); r.y = f2bf_rne(v.y);
    r.z = f2bf_rne(v.z); r.w = f2bf_rne(v.w);
    ((ushort4*)xb)[i] = r;
  }
}

__global__ __launch_bounds__(256) void deq_w_kernel(const int* __restrict__ wp,
                                                    unsigned short* __restrict__ wq) {
  const int n4 = N_DIM * KP / 4;   // 5,636,096 int4-groups
  int i = blockIdx.x * blockDim.x + threadIdx.x;
  const int stride = gridDim.x * blockDim.x;
  for (; i < n4; i += stride) {
    int4 b = ((const int4*)wp)[i];
    u16x8 r;
    r[0] = i2bf(sx4(b.x, 0)); r[1] = i2bf(sx4(b.x, 1));
    r[2] = i2bf(sx4(b.y, 0)); r[3] = i2bf(sx4(b.y, 1));
    r[4] = i2bf(sx4(b.z, 0)); r[5] = i2bf(sx4(b.z, 1));
    r[6] = i2bf(sx4(b.w, 0)); r[7] = i2bf(sx4(b.w, 1));
    ((u16x8*)wq)[i] = r;
  }
}

// ---------------- GEMM ----------------
// MODE 0: xb (bf16) + wq (bf16) pre-converted in ws -> global_load_lds staging
// MODE 1: xb pre-converted; w unpacked inline (reg-staged)
// MODE 2: fully fused (x converted inline, w unpacked inline)
template <int MODE>
__global__ __launch_bounds__(256)
void qgemm_kernel(const float* __restrict__ x, const unsigned short* __restrict__ xb,
                  const int* __restrict__ wp, const unsigned short* __restrict__ wq,
                  const float* __restrict__ scales, const float* __restrict__ bias,
                  float* __restrict__ out) {
  __shared__ __align__(16) unsigned short As[BM * BK];  // linear [row][k], 16KB
  __shared__ __align__(16) unsigned short Bs[BN * BK];  // linear [row][k], 16KB

  const int tid  = threadIdx.x;
  const int lane = tid & 63;
  const int wid  = tid >> 6;

  // XCD-aware chunked swizzle (NBLK % 8 == 0 -> bijective)
  int bid = blockIdx.x;
  int swz = (bid & 7) * (NBLK / 8) + (bid >> 3);
  const int tm = swz & (NTM - 1);   // NTM = 32 (pow2), m fastest
  const int tn = swz >> 5;
  const int m0 = tm * BM, n0 = tn * BN;

  const int wr = wid >> 1, wc = wid & 1;   // 2x2 wave grid, 64x64 per wave
  const int fr = lane & 15;                // fragment row (within 16)
  const int fg = lane >> 4;                // k-group 0..3

  f32x4 acc[4][4] = {};

  for (int kt = 0; kt < K_DIM / BK; ++kt) {
    // -------- issue reg-path global loads early (before barrier) --------
    int4   breg[4];
    float4 areg[8];
    if constexpr (MODE >= 1) {
#pragma unroll
      for (int p = 0; p < 4; ++p) {
        int fl = p * 256 + tid;            // [0,1024)
        int row = fl >> 3, u = fl & 7;     // 8x16B per row (32 int32)
        breg[p] = *(const int4*)(wp + (size_t)(n0 + row) * KP + kt * (BK / 2) + u * 4);
      }
    }
    if constexpr (MODE == 2) {
#pragma unroll
      for (int p = 0; p < 8; ++p) {
        int fl = p * 256 + tid;            // [0,2048)
        int row = fl >> 4, u = fl & 15;    // 16x16B(fp32) per row
        areg[p] = *(const float4*)(x + (size_t)(m0 + row) * K_DIM + kt * BK + u * 4);
      }
    }

    __syncthreads();   // prev iteration's LDS reads complete

    // -------- A tile -> LDS --------
    if constexpr (MODE <= 1) {
#pragma unroll
      for (int p = 0; p < 4; ++p) {
        int t16 = p * 256 + tid;
        int row = t16 >> 3, u = t16 & 7;   // 8x16B per row (64 bf16)
        const unsigned short* g = xb + (size_t)(m0 + row) * K_DIM + kt * BK + u * 8;
        async_copy16((char*)As + (p * 256 + wid * 64) * 16, g);
      }
    } else {
#pragma unroll
      for (int p = 0; p < 8; ++p) {
        int fl = p * 256 + tid;
        int row = fl >> 4, u = fl & 15;
        ushort4 r;
        r.x = f2bf_rne(areg[p].x); r.y = f2bf_rne(areg[p].y);
        r.z = f2bf_rne(areg[p].z); r.w = f2bf_rne(areg[p].w);
        *(ushort4*)((char*)As + row * 128 + u * 8) = r;
      }
    }

    // -------- B tile -> LDS --------
    if constexpr (MODE == 0) {
#pragma unroll
      for (int p = 0; p < 4; ++p) {
        int t16 = p * 256 + tid;
        int row = t16 >> 3, u = t16 & 7;
        const unsigned short* g = wq + (size_t)(n0 + row) * K_DIM + kt * BK + u * 8;
        async_copy16((char*)Bs + (p * 256 + wid * 64) * 16, g);
      }
    } else {
#pragma unroll
      for (int p = 0; p < 4; ++p) {
        int fl = p * 256 + tid;
        int row = fl >> 3, u = fl & 7;
        int4 b = breg[p];
        u16x8 r;
        r[0] = i2bf(sx4(b.x, 0)); r[1] = i2bf(sx4(b.x, 1));
        r[2] = i2bf(sx4(b.y, 0)); r[3] = i2bf(sx4(b.y, 1));
        r[4] = i2bf(sx4(b.z, 0)); r[5] = i2bf(sx4(b.z, 1));
        r[6] = i2bf(sx4(b.w, 0)); r[7] = i2bf(sx4(b.w, 1));
        *(u16x8*)((char*)Bs + row * 128 + u * 16) = r;
      }
    }

    __syncthreads();   // staging visible (drains vmcnt + lgkmcnt)

    // -------- MFMA: 2 k-slabs of 16 MFMAs --------
#pragma unroll
    for (int kk = 0; kk < 2; ++kk) {
      const int kb = kk * 64 + fg * 16;    // byte offset within a row
      bf16x8 af[4], bfv[4];
#pragma unroll
      for (int mi = 0; mi < 4; ++mi) {
        int row = wr * 64 + mi * 16 + fr;
        af[mi] = *(const bf16x8*)((const char*)As + row * 128 + kb);
      }
#pragma unroll
      for (int ni = 0; ni < 4; ++ni) {
        int row = wc * 64 + ni * 16 + fr;
        bfv[ni] = *(const bf16x8*)((const char*)Bs + row * 128 + kb);
      }
#pragma unroll
      for (int mi = 0; mi < 4; ++mi)
#pragma unroll
        for (int ni = 0; ni < 4; ++ni)
          acc[mi][ni] = __builtin_amdgcn_mfma_f32_16x16x32_bf16(af[mi], bfv[ni], acc[mi][ni], 0, 0, 0);
    }
  }

  // -------- epilogue: y = acc*scale[o] + bias[o] --------
  // C/D layout (m89-verified): col = lane&15, row = (lane>>4)*4 + reg
#pragma unroll
  for (int ni = 0; ni < 4; ++ni) {
    const int o = n0 + wc * 64 + ni * 16 + fr;
    const float s = scales[o];
    const float b = bias[o];
#pragma unroll
    for (int mi = 0; mi < 4; ++mi) {
      const int mr = m0 + wr * 64 + mi * 16 + fg * 4;
#pragma unroll
      for (int r = 0; r < 4; ++r) {
        out[(size_t)(mr + r) * N_DIM + o] = acc[mi][ni][r] * s + b;
      }
    }
  }
}

extern "C" void kernel_launch(void* const* d_in, const int* in_sizes, int n_in,
                              void* d_out, int out_size, void* d_ws, size_t ws_size,
                              hipStream_t stream) {
  const float* x  = (const float*)d_in[0];
  const int*   wp = (const int*)d_in[1];
  const float* sc = (const float*)d_in[2];
  const float* bs = (const float*)d_in[3];
  float* out = (float*)d_out;

  const size_t xb_bytes = (size_t)M_DIM * K_DIM * 2;   // 33,554,432
  const size_t wq_bytes = (size_t)N_DIM * K_DIM * 2;   // 90,177,536
  unsigned short* xb = (unsigned short*)d_ws;
  unsigned short* wq = (unsigned short*)((char*)d_ws + xb_bytes);

  if (ws_size >= xb_bytes + wq_bytes) {
    cvt_x_kernel<<<2048, 256, 0, stream>>>(x, xb);
    deq_w_kernel<<<2048, 256, 0, stream>>>(wp, wq);
    qgemm_kernel<0><<<NBLK, 256, 0, stream>>>(x, xb, wp, wq, sc, bs, out);
  } else if (ws_size >= xb_bytes) {
    cvt_x_kernel<<<2048, 256, 0, stream>>>(x, xb);
    qgemm_kernel<1><<<NBLK, 256, 0, stream>>>(x, xb, wp, wq, sc, bs, out);
  } else {
    qgemm_kernel<2><<<NBLK, 256, 0, stream>>>(x, xb, wp, wq, sc, bs, out);
  }
}

// Round 2
// 499.522 us; speedup vs baseline: 1.2799x; 1.2799x over previous
//
#include <hip/hip_runtime.h>
#include <hip/hip_bf16.h>
#include <stdint.h>

// Problem dims
#define M_DIM 4096      // 2*2048 rows of x
#define K_DIM 4096
#define N_DIM 11008
#define KP    2048      // K/2 packed int32 per w row

// ---------------- 8-phase 256x256 GEMM geometry ----------------
#define BK2   64
#define NKT   (K_DIM/BK2)        // 64 K-tiles
#define NTM2  (M_DIM/256)        // 16
#define NTN2  (N_DIM/256)        // 43
#define NBLK2 (NTM2*NTN2)        // 688  (%8==0 -> bijective XCD swizzle)
#define HT_BYTES 16384           // half-tile: 128 rows x 64 bf16

// ---------------- old 128x128 fallback geometry ----------------
#define BM 128
#define BN 128
#define BK 64
#define NTM (M_DIM/BM)
#define NTN (N_DIM/BN)
#define NBLK (NTM*NTN)

typedef __attribute__((ext_vector_type(8))) short  bf16x8;
typedef __attribute__((ext_vector_type(4))) float  f32x4;
typedef __attribute__((ext_vector_type(8))) unsigned short u16x8;

typedef const void __attribute__((address_space(1)))* gas_ptr;
typedef void __attribute__((address_space(3)))* las_ptr;

__device__ __forceinline__ void async_copy16(void* lds, const void* g) {
  __builtin_amdgcn_global_load_lds((gas_ptr)g, (las_ptr)lds, 16, 0, 0);
}

__device__ __forceinline__ unsigned short f2bf_rne(float f) {
  uint32_t u = __builtin_bit_cast(uint32_t, f);
  u += 0x7FFFu + ((u >> 16) & 1u);
  return (unsigned short)(u >> 16);
}
__device__ __forceinline__ unsigned short i2bf(int v) {
  float f = (float)v;
  return (unsigned short)(__builtin_bit_cast(uint32_t, f) >> 16);
}
__device__ __forceinline__ int sx4(int b, int which) {
  return ((int)((uint32_t)b << (28 - 4 * which))) >> 28;
}
// st_16x32 swizzle (m201): XOR byte-bit-5 with bit-9; involution, 16B-chunk-safe
__device__ __forceinline__ int swz(int o) { return o ^ (((o >> 9) & 1) << 5); }

// ---------------- pre-pass: tiled + swizzled half-tile images ----------------
// A image: [tm][kt][h] half-tiles of 16KB; within: swz(row*128 + c8*16)
__global__ __launch_bounds__(256) void cvt_x_tiled(const float* __restrict__ x,
                                                   unsigned short* __restrict__ wsA) {
  const int total = NTM2 * NKT * 2 * 1024;   // 16B chunks
  for (int i = blockIdx.x * blockDim.x + threadIdx.x; i < total;
       i += gridDim.x * blockDim.x) {
    int cin = i & 1023;
    int h   = (i >> 10) & 1;
    int kt  = (i >> 11) & 63;
    int tm  = i >> 17;
    int row = cin >> 3, c8 = cin & 7;
    const float* src = x + (size_t)(tm * 256 + h * 128 + row) * K_DIM + kt * 64 + c8 * 8;
    float4 v0 = *(const float4*)src;
    float4 v1 = *(const float4*)(src + 4);
    u16x8 r;
    r[0] = f2bf_rne(v0.x); r[1] = f2bf_rne(v0.y); r[2] = f2bf_rne(v0.z); r[3] = f2bf_rne(v0.w);
    r[4] = f2bf_rne(v1.x); r[5] = f2bf_rne(v1.y); r[6] = f2bf_rne(v1.z); r[7] = f2bf_rne(v1.w);
    *(u16x8*)((char*)wsA + (size_t)(i >> 10) * HT_BYTES + swz(cin * 16)) = r;
  }
}

// B image: [tn][kt][h] half-tiles; dequant int4 nibbles -> exact bf16 q in [-8,7]
__global__ __launch_bounds__(256) void deq_w_tiled(const int* __restrict__ wp,
                                                   unsigned short* __restrict__ wsB) {
  const int total = NTN2 * NKT * 2 * 1024;
  for (int i = blockIdx.x * blockDim.x + threadIdx.x; i < total;
       i += gridDim.x * blockDim.x) {
    int cin = i & 1023;
    int h   = (i >> 10) & 1;
    int kt  = (i >> 11) & 63;
    int tn  = i >> 17;
    int row = cin >> 3, c8 = cin & 7;
    int4 b = *(const int4*)(wp + (size_t)(tn * 256 + h * 128 + row) * KP + kt * 32 + c8 * 4);
    u16x8 r;
    r[0] = i2bf(sx4(b.x, 0)); r[1] = i2bf(sx4(b.x, 1));
    r[2] = i2bf(sx4(b.y, 0)); r[3] = i2bf(sx4(b.y, 1));
    r[4] = i2bf(sx4(b.z, 0)); r[5] = i2bf(sx4(b.z, 1));
    r[6] = i2bf(sx4(b.w, 0)); r[7] = i2bf(sx4(b.w, 1));
    *(u16x8*)((char*)wsB + (size_t)(i >> 10) * HT_BYTES + swz(cin * 16)) = r;
  }
}

// ---------------- 8-phase 256x256 GEMM (MODE 0) ----------------
__global__ __launch_bounds__(512, 2)
void qgemm8(const unsigned short* __restrict__ wsA, const unsigned short* __restrict__ wsB,
            const float* __restrict__ scales, const float* __restrict__ bias,
            float* __restrict__ out) {
  __shared__ __align__(16) char smem[131072];  // 2 buf x (A 32KB + B 32KB)

  const int tid  = threadIdx.x;
  const int lane = tid & 63, wid = tid >> 6;
  const int wr = wid >> 2, wc = wid & 3;       // 2x4 wave grid; per-wave 128x64
  const int fr = lane & 15, fg = lane >> 4;

  int bid = blockIdx.x;
  int id  = (bid & 7) * (NBLK2 / 8) + (bid >> 3);   // bijective XCD chunking
  int tm  = id / NTN2, tn = id % NTN2;

  const char* gA = (const char*)wsA + (size_t)tm * (NKT * 2) * HT_BYTES;
  const char* gB = (const char*)wsB + (size_t)tn * (NKT * 2) * HT_BYTES;

#define STAGE(ldsoff, src) do { \
    async_copy16(smem + (ldsoff) + (wid * 64) * 16, (src) + (wid * 64 + lane) * 16); \
    async_copy16(smem + (ldsoff) + (512 + wid * 64) * 16, (src) + (512 + wid * 64 + lane) * 16); \
  } while (0)
#define STAGE_A(buf, h, kt) STAGE((buf) * 65536 + (h) * HT_BYTES, gA + ((kt) * 2 + (h)) * HT_BYTES)
#define STAGE_B(buf, h, kt) STAGE((buf) * 65536 + 32768 + (h) * HT_BYTES, gB + ((kt) * 2 + (h)) * HT_BYTES)

  f32x4  acc[8][4] = {};
  bf16x8 aR[4][2];        // one A reg-half (mi 0-3 of sel) x kk
  bf16x8 bR[2][2][2];     // [bn][nl][kk]; B0 stays live through ph3

#define LOAD_A(buf, sel) do { \
    const char* _ab = smem + (buf) * 65536 + wr * HT_BYTES; \
    _Pragma("unroll") for (int i = 0; i < 4; ++i) { \
      int rA = (sel) * 64 + i * 16 + fr; \
      int xr = ((rA >> 2) & 1) << 5; \
      _Pragma("unroll") for (int kk = 0; kk < 2; ++kk) \
        aR[i][kk] = *(const bf16x8*)(_ab + ((rA * 128 + kk * 64 + fg * 16) ^ xr)); \
    } } while (0)
#define LOAD_B(buf, bn) do { \
    const char* _bb = smem + (buf) * 65536 + 32768 + (wc >> 1) * HT_BYTES; \
    _Pragma("unroll") for (int nl = 0; nl < 2; ++nl) { \
      int rB = (wc & 1) * 64 + ((bn) * 2 + nl) * 16 + fr; \
      int xr = ((rB >> 2) & 1) << 5; \
      _Pragma("unroll") for (int kk = 0; kk < 2; ++kk) \
        bR[bn][nl][kk] = *(const bf16x8*)(_bb + ((rB * 128 + kk * 64 + fg * 16) ^ xr)); \
    } } while (0)
#define MMQ(sel, bn) do { \
    _Pragma("unroll") for (int kk = 0; kk < 2; ++kk) \
    _Pragma("unroll") for (int i = 0; i < 4; ++i) \
    _Pragma("unroll") for (int nl = 0; nl < 2; ++nl) \
      acc[(sel) * 4 + i][(bn) * 2 + nl] = __builtin_amdgcn_mfma_f32_16x16x32_bf16( \
          aR[i][kk], bR[bn][nl][kk], acc[(sel) * 4 + i][(bn) * 2 + nl], 0, 0, 0); \
  } while (0)

#define PH_BAR do { __builtin_amdgcn_s_barrier(); __builtin_amdgcn_sched_barrier(0); } while (0)
#define LGKM0 asm volatile("s_waitcnt lgkmcnt(0)" ::: "memory")
#define VMC4  asm volatile("s_waitcnt vmcnt(4)" ::: "memory")
#define PRIO1 __builtin_amdgcn_s_setprio(1)
#define PRIO0 __builtin_amdgcn_s_setprio(0)

  // Prologue: buf0 <- tile0 (B0,B1,A0,A1), buf1 <- tile1 (B0,B1). 12 loads.
  STAGE_B(0, 0, 0); STAGE_B(0, 1, 0);
  STAGE_A(0, 0, 0); STAGE_A(0, 1, 0);
  STAGE_B(1, 0, 1); STAGE_B(1, 1, 1);
  VMC4;        // drain buf0's 8 loads, keep buf1's 4
  PH_BAR;

  for (int t = 0; t < NKT / 2; ++t) {
    const int k1 = 2 * t + 1;
    const int k2 = (2 * t + 2 < NKT) ? 2 * t + 2 : NKT - 1;  // tail clamp (never read)
    const int k3 = (2 * t + 3 < NKT) ? 2 * t + 3 : NKT - 1;

    // ---- ph0: Q(A0,B0) of buf0 ----
    LOAD_A(0, 0); LOAD_B(0, 0);
    STAGE_A(1, 0, k1);
    PH_BAR; LGKM0;
    PRIO1; MMQ(0, 0); PRIO0;
    PH_BAR;
    // ---- ph1: Q(A0,B1) ----
    LOAD_B(0, 1);
    STAGE_A(1, 1, k1);
    PH_BAR; LGKM0;
    PRIO1; MMQ(0, 1); PRIO0;
    PH_BAR;
    // ---- ph2: Q(A1,B1) ----
    LOAD_A(0, 1);
    STAGE_B(0, 0, k2);          // buf0.B freed after ph1
    PH_BAR; LGKM0;
    PRIO1; MMQ(1, 1); PRIO0;
    PH_BAR;
    // ---- ph3: Q(A1,B0) from regs; guard buf1 for ph4-7 ----
    STAGE_B(0, 1, k2);
    VMC4;                        // drain through buf1.A-h1 (ph1 of this iter)
    PH_BAR;
    PRIO1; MMQ(1, 0); PRIO0;
    PH_BAR;
    // ---- ph4: Q(A0,B0) of buf1 ----
    LOAD_A(1, 0); LOAD_B(1, 0);
    STAGE_A(0, 0, k2);           // buf0.A freed after ph2
    PH_BAR; LGKM0;
    PRIO1; MMQ(0, 0); PRIO0;
    PH_BAR;
    // ---- ph5: Q(A0,B1) ----
    LOAD_B(1, 1);
    STAGE_A(0, 1, k2);
    PH_BAR; LGKM0;
    PRIO1; MMQ(0, 1); PRIO0;
    PH_BAR;
    // ---- ph6: Q(A1,B1) ----
    LOAD_A(1, 1);
    STAGE_B(1, 0, k3);           // buf1.B freed after ph5
    PH_BAR; LGKM0;
    PRIO1; MMQ(1, 1); PRIO0;
    PH_BAR;
    // ---- ph7: Q(A1,B0) from regs; guard buf0 for next ph0-3 ----
    STAGE_B(1, 1, k3);
    VMC4;                        // drain through buf0.A-h1 (ph5 of this iter)
    PH_BAR;
    PRIO1; MMQ(1, 0); PRIO0;
    PH_BAR;
  }

  // ---- epilogue: y = acc*scale + bias; C layout col=lane&15, row=fg*4+reg ----
  const int m0 = tm * 256, n0 = tn * 256;
#pragma unroll
  for (int ni = 0; ni < 4; ++ni) {
    const int o = n0 + wc * 64 + ni * 16 + fr;
    const float s = scales[o];
    const float b = bias[o];
#pragma unroll
    for (int mi = 0; mi < 8; ++mi) {
      const int mr = m0 + wr * 128 + mi * 16 + fg * 4;
#pragma unroll
      for (int r = 0; r < 4; ++r)
        out[(size_t)(mr + r) * N_DIM + o] = acc[mi][ni][r] * s + b;
    }
  }
#undef STAGE
#undef STAGE_A
#undef STAGE_B
#undef LOAD_A
#undef LOAD_B
#undef MMQ
#undef PH_BAR
#undef LGKM0
#undef VMC4
#undef PRIO1
#undef PRIO0
}

// ---------------- fallback pre-pass (linear xb) + 128x128 GEMM ----------------
__global__ __launch_bounds__(256) void cvt_x_kernel(const float* __restrict__ x,
                                                    unsigned short* __restrict__ xb) {
  const int n4 = M_DIM * K_DIM / 4;
  int i = blockIdx.x * blockDim.x + threadIdx.x;
  const int stride = gridDim.x * blockDim.x;
  for (; i < n4; i += stride) {
    float4 v = ((const float4*)x)[i];
    ushort4 r;
    r.x = f2bf_rne(v.x); r.y = f2bf_rne(v.y);
    r.z = f2bf_rne(v.z); r.w = f2bf_rne(v.w);
    ((ushort4*)xb)[i] = r;
  }
}

template <int MODE>
__global__ __launch_bounds__(256)
void qgemm_kernel(const float* __restrict__ x, const unsigned short* __restrict__ xb,
                  const int* __restrict__ wp,
                  const float* __restrict__ scales, const float* __restrict__ bias,
                  float* __restrict__ out) {
  __shared__ __align__(16) unsigned short As[BM * BK];
  __shared__ __align__(16) unsigned short Bs[BN * BK];
  const int tid  = threadIdx.x;
  const int lane = tid & 63;
  const int wid  = tid >> 6;
  int bid = blockIdx.x;
  int swzb = (bid & 7) * (NBLK / 8) + (bid >> 3);
  const int tm = swzb & (NTM - 1);
  const int tn = swzb >> 5;
  const int m0 = tm * BM, n0 = tn * BN;
  const int wr = wid >> 1, wc = wid & 1;
  const int fr = lane & 15;
  const int fg = lane >> 4;
  f32x4 acc[4][4] = {};

  for (int kt = 0; kt < K_DIM / BK; ++kt) {
    int4   breg[4];
    float4 areg[8];
#pragma unroll
    for (int p = 0; p < 4; ++p) {
      int fl = p * 256 + tid;
      int row = fl >> 3, u = fl & 7;
      breg[p] = *(const int4*)(wp + (size_t)(n0 + row) * KP + kt * (BK / 2) + u * 4);
    }
    if constexpr (MODE == 2) {
#pragma unroll
      for (int p = 0; p < 8; ++p) {
        int fl = p * 256 + tid;
        int row = fl >> 4, u = fl & 15;
        areg[p] = *(const float4*)(x + (size_t)(m0 + row) * K_DIM + kt * BK + u * 4);
      }
    }
    __syncthreads();
    if constexpr (MODE == 1) {
#pragma unroll
      for (int p = 0; p < 4; ++p) {
        int t16 = p * 256 + tid;
        int row = t16 >> 3, u = t16 & 7;
        const unsigned short* g = xb + (size_t)(m0 + row) * K_DIM + kt * BK + u * 8;
        async_copy16((char*)As + (p * 256 + wid * 64) * 16, g);
      }
    } else {
#pragma unroll
      for (int p = 0; p < 8; ++p) {
        int fl = p * 256 + tid;
        int row = fl >> 4, u = fl & 15;
        ushort4 r;
        r.x = f2bf_rne(areg[p].x); r.y = f2bf_rne(areg[p].y);
        r.z = f2bf_rne(areg[p].z); r.w = f2bf_rne(areg[p].w);
        *(ushort4*)((char*)As + row * 128 + u * 8) = r;
      }
    }
#pragma unroll
    for (int p = 0; p < 4; ++p) {
      int fl = p * 256 + tid;
      int row = fl >> 3, u = fl & 7;
      int4 b = breg[p];
      u16x8 r;
      r[0] = i2bf(sx4(b.x, 0)); r[1] = i2bf(sx4(b.x, 1));
      r[2] = i2bf(sx4(b.y, 0)); r[3] = i2bf(sx4(b.y, 1));
      r[4] = i2bf(sx4(b.z, 0)); r[5] = i2bf(sx4(b.z, 1));
      r[6] = i2bf(sx4(b.w, 0)); r[7] = i2bf(sx4(b.w, 1));
      *(u16x8*)((char*)Bs + row * 128 + u * 16) = r;
    }
    __syncthreads();
#pragma unroll
    for (int kk = 0; kk < 2; ++kk) {
      const int kb = kk * 64 + fg * 16;
      bf16x8 af[4], bfv[4];
#pragma unroll
      for (int mi = 0; mi < 4; ++mi) {
        int row = wr * 64 + mi * 16 + fr;
        af[mi] = *(const bf16x8*)((const char*)As + row * 128 + kb);
      }
#pragma unroll
      for (int ni = 0; ni < 4; ++ni) {
        int row = wc * 64 + ni * 16 + fr;
        bfv[ni] = *(const bf16x8*)((const char*)Bs + row * 128 + kb);
      }
#pragma unroll
      for (int mi = 0; mi < 4; ++mi)
#pragma unroll
        for (int ni = 0; ni < 4; ++ni)
          acc[mi][ni] = __builtin_amdgcn_mfma_f32_16x16x32_bf16(af[mi], bfv[ni], acc[mi][ni], 0, 0, 0);
    }
  }
#pragma unroll
  for (int ni = 0; ni < 4; ++ni) {
    const int o = n0 + wc * 64 + ni * 16 + fr;
    const float s = scales[o];
    const float b = bias[o];
#pragma unroll
    for (int mi = 0; mi < 4; ++mi) {
      const int mr = m0 + wr * 64 + mi * 16 + fg * 4;
#pragma unroll
      for (int r = 0; r < 4; ++r)
        out[(size_t)(mr + r) * N_DIM + o] = acc[mi][ni][r] * s + b;
    }
  }
}

extern "C" void kernel_launch(void* const* d_in, const int* in_sizes, int n_in,
                              void* d_out, int out_size, void* d_ws, size_t ws_size,
                              hipStream_t stream) {
  const float* x  = (const float*)d_in[0];
  const int*   wp = (const int*)d_in[1];
  const float* sc = (const float*)d_in[2];
  const float* bs = (const float*)d_in[3];
  float* out = (float*)d_out;

  const size_t a_bytes = (size_t)NTM2 * NKT * 2 * HT_BYTES;  // 33,554,432
  const size_t b_bytes = (size_t)NTN2 * NKT * 2 * HT_BYTES;  // 90,177,536
  unsigned short* wsA = (unsigned short*)d_ws;
  unsigned short* wsB = (unsigned short*)((char*)d_ws + a_bytes);

  if (ws_size >= a_bytes + b_bytes) {
    cvt_x_tiled<<<2048, 256, 0, stream>>>(x, wsA);
    deq_w_tiled<<<2048, 256, 0, stream>>>(wp, wsB);
    qgemm8<<<NBLK2, 512, 0, stream>>>(wsA, wsB, sc, bs, out);
  } else if (ws_size >= a_bytes) {
    cvt_x_kernel<<<2048, 256, 0, stream>>>(x, wsA);
    qgemm_kernel<1><<<NBLK, 256, 0, stream>>>(x, wsA, wp, sc, bs, out);
  } else {
    qgemm_kernel<2><<<NBLK, 256, 0, stream>>>(x, wsA, wp, sc, bs, out);
  }
}

// Round 3
// 463.968 us; speedup vs baseline: 1.3780x; 1.0766x over previous
//
#include <hip/hip_runtime.h>
#include <hip/hip_bf16.h>
#include <stdint.h>

// Problem dims
#define M_DIM 4096      // 2*2048 rows of x
#define K_DIM 4096
#define N_DIM 11008
#define KP    2048      // K/2 packed int32 per w row

// ---------------- 8-phase 256x256 GEMM geometry ----------------
#define BK2   64
#define NKT   (K_DIM/BK2)        // 64 K-tiles
#define NTM2  (M_DIM/256)        // 16
#define NTN2  (N_DIM/256)        // 43
#define NBLK2 (NTM2*NTN2)        // 688  (%8==0 -> bijective XCD swizzle)
#define HT_BYTES 16384           // half-tile: 128 rows x 64 bf16

// ---------------- old 128x128 fallback geometry ----------------
#define BM 128
#define BN 128
#define BK 64
#define NTM (M_DIM/BM)
#define NTN (N_DIM/BN)
#define NBLK (NTM*NTN)

typedef __attribute__((ext_vector_type(8))) short  bf16x8;
typedef __attribute__((ext_vector_type(4))) float  f32x4;
typedef __attribute__((ext_vector_type(8))) unsigned short u16x8;

typedef const void __attribute__((address_space(1)))* gas_ptr;
typedef void __attribute__((address_space(3)))* las_ptr;

__device__ __forceinline__ void async_copy16(void* lds, const void* g) {
  __builtin_amdgcn_global_load_lds((gas_ptr)g, (las_ptr)lds, 16, 0, 0);
}

__device__ __forceinline__ unsigned short f2bf_rne(float f) {
  uint32_t u = __builtin_bit_cast(uint32_t, f);
  u += 0x7FFFu + ((u >> 16) & 1u);
  return (unsigned short)(u >> 16);
}
__device__ __forceinline__ unsigned short i2bf(int v) {
  float f = (float)v;
  return (unsigned short)(__builtin_bit_cast(uint32_t, f) >> 16);
}
__device__ __forceinline__ int sx4(int b, int which) {
  return ((int)((uint32_t)b << (28 - 4 * which))) >> 28;
}
// Bank swizzle: XOR 16B-slot index (bits [6:4]) with row&7 (row = bits [13:7]).
// Within any 16-lane read group (fr=0..15 at fixed fg,kk) the 8 slots are each
// hit exactly twice -> 2 lanes/bank -> conflict-free (m136). Involution.
__device__ __forceinline__ int swz(int o) { return o ^ (((o >> 7) & 7) << 4); }

// ---------------- pre-pass: tiled + swizzled half-tile images ----------------
// A image: [tm][kt][h] half-tiles of 16KB; within: swz(row*128 + c8*16)
__global__ __launch_bounds__(256) void cvt_x_tiled(const float* __restrict__ x,
                                                   unsigned short* __restrict__ wsA) {
  const int total = NTM2 * NKT * 2 * 1024;   // 16B chunks
  for (int i = blockIdx.x * blockDim.x + threadIdx.x; i < total;
       i += gridDim.x * blockDim.x) {
    int cin = i & 1023;
    int h   = (i >> 10) & 1;
    int kt  = (i >> 11) & 63;
    int tm  = i >> 17;
    int row = cin >> 3, c8 = cin & 7;
    const float* src = x + (size_t)(tm * 256 + h * 128 + row) * K_DIM + kt * 64 + c8 * 8;
    float4 v0 = *(const float4*)src;
    float4 v1 = *(const float4*)(src + 4);
    u16x8 r;
    r[0] = f2bf_rne(v0.x); r[1] = f2bf_rne(v0.y); r[2] = f2bf_rne(v0.z); r[3] = f2bf_rne(v0.w);
    r[4] = f2bf_rne(v1.x); r[5] = f2bf_rne(v1.y); r[6] = f2bf_rne(v1.z); r[7] = f2bf_rne(v1.w);
    *(u16x8*)((char*)wsA + (size_t)(i >> 10) * HT_BYTES + swz(cin * 16)) = r;
  }
}

// B image: [tn][kt][h] half-tiles; dequant int4 nibbles -> exact bf16 q in [-8,7]
__global__ __launch_bounds__(256) void deq_w_tiled(const int* __restrict__ wp,
                                                   unsigned short* __restrict__ wsB) {
  const int total = NTN2 * NKT * 2 * 1024;
  for (int i = blockIdx.x * blockDim.x + threadIdx.x; i < total;
       i += gridDim.x * blockDim.x) {
    int cin = i & 1023;
    int h   = (i >> 10) & 1;
    int kt  = (i >> 11) & 63;
    int tn  = i >> 17;
    int row = cin >> 3, c8 = cin & 7;
    int4 b = *(const int4*)(wp + (size_t)(tn * 256 + h * 128 + row) * KP + kt * 32 + c8 * 4);
    u16x8 r;
    r[0] = i2bf(sx4(b.x, 0)); r[1] = i2bf(sx4(b.x, 1));
    r[2] = i2bf(sx4(b.y, 0)); r[3] = i2bf(sx4(b.y, 1));
    r[4] = i2bf(sx4(b.z, 0)); r[5] = i2bf(sx4(b.z, 1));
    r[6] = i2bf(sx4(b.w, 0)); r[7] = i2bf(sx4(b.w, 1));
    *(u16x8*)((char*)wsB + (size_t)(i >> 10) * HT_BYTES + swz(cin * 16)) = r;
  }
}

// ---------------- 8-phase 256x256 GEMM (MODE 0) ----------------
__global__ __launch_bounds__(512, 2)
void qgemm8(const unsigned short* __restrict__ wsA, const unsigned short* __restrict__ wsB,
            const float* __restrict__ scales, const float* __restrict__ bias,
            float* __restrict__ out) {
  __shared__ __align__(16) char smem[131072];  // 2 buf x (A 32KB + B 32KB)

  const int tid  = threadIdx.x;
  const int lane = tid & 63, wid = tid >> 6;
  const int wr = wid >> 2, wc = wid & 3;       // 2x4 wave grid; per-wave 128x64
  const int fr = lane & 15, fg = lane >> 4;

  int bid = blockIdx.x;
  int id  = (bid & 7) * (NBLK2 / 8) + (bid >> 3);   // bijective XCD chunking
  int tm  = id / NTN2, tn = id % NTN2;

  const char* gA = (const char*)wsA + (size_t)tm * (NKT * 2) * HT_BYTES;
  const char* gB = (const char*)wsB + (size_t)tn * (NKT * 2) * HT_BYTES;

#define STAGE(ldsoff, src) do { \
    async_copy16(smem + (ldsoff) + (wid * 64) * 16, (src) + (wid * 64 + lane) * 16); \
    async_copy16(smem + (ldsoff) + (512 + wid * 64) * 16, (src) + (512 + wid * 64 + lane) * 16); \
  } while (0)
#define STAGE_A(buf, h, kt) STAGE((buf) * 65536 + (h) * HT_BYTES, gA + ((kt) * 2 + (h)) * HT_BYTES)
#define STAGE_B(buf, h, kt) STAGE((buf) * 65536 + 32768 + (h) * HT_BYTES, gB + ((kt) * 2 + (h)) * HT_BYTES)

  f32x4  acc[8][4] = {};
  bf16x8 aR[4][2];        // one A reg-half (mi 0-3 of sel) x kk
  bf16x8 bR[2][2][2];     // [bn][nl][kk]; B0 stays live through ph3

#define LOAD_A(buf, sel) do { \
    const char* _ab = smem + (buf) * 65536 + wr * HT_BYTES; \
    _Pragma("unroll") for (int i = 0; i < 4; ++i) { \
      int rA = (sel) * 64 + i * 16 + fr; \
      int xr = (rA & 7) << 4; \
      _Pragma("unroll") for (int kk = 0; kk < 2; ++kk) \
        aR[i][kk] = *(const bf16x8*)(_ab + ((rA * 128 + kk * 64 + fg * 16) ^ xr)); \
    } } while (0)
#define LOAD_B(buf, bn) do { \
    const char* _bb = smem + (buf) * 65536 + 32768 + (wc >> 1) * HT_BYTES; \
    _Pragma("unroll") for (int nl = 0; nl < 2; ++nl) { \
      int rB = (wc & 1) * 64 + ((bn) * 2 + nl) * 16 + fr; \
      int xr = (rB & 7) << 4; \
      _Pragma("unroll") for (int kk = 0; kk < 2; ++kk) \
        bR[bn][nl][kk] = *(const bf16x8*)(_bb + ((rB * 128 + kk * 64 + fg * 16) ^ xr)); \
    } } while (0)
#define MMQ(sel, bn) do { \
    _Pragma("unroll") for (int kk = 0; kk < 2; ++kk) \
    _Pragma("unroll") for (int i = 0; i < 4; ++i) \
    _Pragma("unroll") for (int nl = 0; nl < 2; ++nl) \
      acc[(sel) * 4 + i][(bn) * 2 + nl] = __builtin_amdgcn_mfma_f32_16x16x32_bf16( \
          aR[i][kk], bR[bn][nl][kk], acc[(sel) * 4 + i][(bn) * 2 + nl], 0, 0, 0); \
  } while (0)

#define PH_BAR do { __builtin_amdgcn_s_barrier(); __builtin_amdgcn_sched_barrier(0); } while (0)
#define LGKM0 asm volatile("s_waitcnt lgkmcnt(0)" ::: "memory")
#define VMC4  asm volatile("s_waitcnt vmcnt(4)" ::: "memory")
#define PRIO1 __builtin_amdgcn_s_setprio(1)
#define PRIO0 __builtin_amdgcn_s_setprio(0)

  // Prologue: buf0 <- tile0 (B0,B1,A0,A1), buf1 <- tile1 (B0,B1). 12 loads.
  STAGE_B(0, 0, 0); STAGE_B(0, 1, 0);
  STAGE_A(0, 0, 0); STAGE_A(0, 1, 0);
  STAGE_B(1, 0, 1); STAGE_B(1, 1, 1);
  VMC4;        // drain buf0's 8 loads, keep buf1's 4
  PH_BAR;

  for (int t = 0; t < NKT / 2; ++t) {
    const int k1 = 2 * t + 1;
    const int k2 = (2 * t + 2 < NKT) ? 2 * t + 2 : NKT - 1;  // tail clamp (never read)
    const int k3 = (2 * t + 3 < NKT) ? 2 * t + 3 : NKT - 1;

    // ---- ph0: Q(A0,B0) of buf0 ----
    LOAD_A(0, 0); LOAD_B(0, 0);
    STAGE_A(1, 0, k1);
    PH_BAR; LGKM0;
    PRIO1; MMQ(0, 0); PRIO0;
    PH_BAR;
    // ---- ph1: Q(A0,B1) ----
    LOAD_B(0, 1);
    STAGE_A(1, 1, k1);
    PH_BAR; LGKM0;
    PRIO1; MMQ(0, 1); PRIO0;
    PH_BAR;
    // ---- ph2: Q(A1,B1) ----
    LOAD_A(0, 1);
    STAGE_B(0, 0, k2);          // buf0.B freed after ph1
    PH_BAR; LGKM0;
    PRIO1; MMQ(1, 1); PRIO0;
    PH_BAR;
    // ---- ph3: Q(A1,B0) from regs; guard buf1 for ph4-7 ----
    STAGE_B(0, 1, k2);
    VMC4;                        // drain through buf1.A-h1 (ph1 of this iter)
    PH_BAR;
    PRIO1; MMQ(1, 0); PRIO0;
    PH_BAR;
    // ---- ph4: Q(A0,B0) of buf1 ----
    LOAD_A(1, 0); LOAD_B(1, 0);
    STAGE_A(0, 0, k2);           // buf0.A freed after ph2
    PH_BAR; LGKM0;
    PRIO1; MMQ(0, 0); PRIO0;
    PH_BAR;
    // ---- ph5: Q(A0,B1) ----
    LOAD_B(1, 1);
    STAGE_A(0, 1, k2);
    PH_BAR; LGKM0;
    PRIO1; MMQ(0, 1); PRIO0;
    PH_BAR;
    // ---- ph6: Q(A1,B1) ----
    LOAD_A(1, 1);
    STAGE_B(1, 0, k3);           // buf1.B freed after ph5
    PH_BAR; LGKM0;
    PRIO1; MMQ(1, 1); PRIO0;
    PH_BAR;
    // ---- ph7: Q(A1,B0) from regs; guard buf0 for next ph0-3 ----
    STAGE_B(1, 1, k3);
    VMC4;                        // drain through buf0.A-h1 (ph5 of this iter)
    PH_BAR;
    PRIO1; MMQ(1, 0); PRIO0;
    PH_BAR;
  }

  // ---- epilogue: y = acc*scale + bias; C layout col=lane&15, row=fg*4+reg ----
  const int m0 = tm * 256, n0 = tn * 256;
#pragma unroll
  for (int ni = 0; ni < 4; ++ni) {
    const int o = n0 + wc * 64 + ni * 16 + fr;
    const float s = scales[o];
    const float b = bias[o];
#pragma unroll
    for (int mi = 0; mi < 8; ++mi) {
      const int mr = m0 + wr * 128 + mi * 16 + fg * 4;
#pragma unroll
      for (int r = 0; r < 4; ++r)
        out[(size_t)(mr + r) * N_DIM + o] = acc[mi][ni][r] * s + b;
    }
  }
#undef STAGE
#undef STAGE_A
#undef STAGE_B
#undef LOAD_A
#undef LOAD_B
#undef MMQ
#undef PH_BAR
#undef LGKM0
#undef VMC4
#undef PRIO1
#undef PRIO0
}

// ---------------- fallback pre-pass (linear xb) + 128x128 GEMM ----------------
__global__ __launch_bounds__(256) void cvt_x_kernel(const float* __restrict__ x,
                                                    unsigned short* __restrict__ xb) {
  const int n4 = M_DIM * K_DIM / 4;
  int i = blockIdx.x * blockDim.x + threadIdx.x;
  const int stride = gridDim.x * blockDim.x;
  for (; i < n4; i += stride) {
    float4 v = ((const float4*)x)[i];
    ushort4 r;
    r.x = f2bf_rne(v.x); r.y = f2bf_rne(v.y);
    r.z = f2bf_rne(v.z); r.w = f2bf_rne(v.w);
    ((ushort4*)xb)[i] = r;
  }
}

template <int MODE>
__global__ __launch_bounds__(256)
void qgemm_kernel(const float* __restrict__ x, const unsigned short* __restrict__ xb,
                  const int* __restrict__ wp,
                  const float* __restrict__ scales, const float* __restrict__ bias,
                  float* __restrict__ out) {
  __shared__ __align__(16) unsigned short As[BM * BK];
  __shared__ __align__(16) unsigned short Bs[BN * BK];
  const int tid  = threadIdx.x;
  const int lane = tid & 63;
  const int wid  = tid >> 6;
  int bid = blockIdx.x;
  int swzb = (bid & 7) * (NBLK / 8) + (bid >> 3);
  const int tm = swzb & (NTM - 1);
  const int tn = swzb >> 5;
  const int m0 = tm * BM, n0 = tn * BN;
  const int wr = wid >> 1, wc = wid & 1;
  const int fr = lane & 15;
  const int fg = lane >> 4;
  f32x4 acc[4][4] = {};

  for (int kt = 0; kt < K_DIM / BK; ++kt) {
    int4   breg[4];
    float4 areg[8];
#pragma unroll
    for (int p = 0; p < 4; ++p) {
      int fl = p * 256 + tid;
      int row = fl >> 3, u = fl & 7;
      breg[p] = *(const int4*)(wp + (size_t)(n0 + row) * KP + kt * (BK / 2) + u * 4);
    }
    if constexpr (MODE == 2) {
#pragma unroll
      for (int p = 0; p < 8; ++p) {
        int fl = p * 256 + tid;
        int row = fl >> 4, u = fl & 15;
        areg[p] = *(const float4*)(x + (size_t)(m0 + row) * K_DIM + kt * BK + u * 4);
      }
    }
    __syncthreads();
    if constexpr (MODE == 1) {
#pragma unroll
      for (int p = 0; p < 4; ++p) {
        int t16 = p * 256 + tid;
        int row = t16 >> 3, u = t16 & 7;
        const unsigned short* g = xb + (size_t)(m0 + row) * K_DIM + kt * BK + u * 8;
        async_copy16((char*)As + (p * 256 + wid * 64) * 16, g);
      }
    } else {
#pragma unroll
      for (int p = 0; p < 8; ++p) {
        int fl = p * 256 + tid;
        int row = fl >> 4, u = fl & 15;
        ushort4 r;
        r.x = f2bf_rne(areg[p].x); r.y = f2bf_rne(areg[p].y);
        r.z = f2bf_rne(areg[p].z); r.w = f2bf_rne(areg[p].w);
        *(ushort4*)((char*)As + row * 128 + u * 8) = r;
      }
    }
#pragma unroll
    for (int p = 0; p < 4; ++p) {
      int fl = p * 256 + tid;
      int row = fl >> 3, u = fl & 7;
      int4 b = breg[p];
      u16x8 r;
      r[0] = i2bf(sx4(b.x, 0)); r[1] = i2bf(sx4(b.x, 1));
      r[2] = i2bf(sx4(b.y, 0)); r[3] = i2bf(sx4(b.y, 1));
      r[4] = i2bf(sx4(b.z, 0)); r[5] = i2bf(sx4(b.z, 1));
      r[6] = i2bf(sx4(b.w, 0)); r[7] = i2bf(sx4(b.w, 1));
      *(u16x8*)((char*)Bs + row * 128 + u * 16) = r;
    }
    __syncthreads();
#pragma unroll
    for (int kk = 0; kk < 2; ++kk) {
      const int kb = kk * 64 + fg * 16;
      bf16x8 af[4], bfv[4];
#pragma unroll
      for (int mi = 0; mi < 4; ++mi) {
        int row = wr * 64 + mi * 16 + fr;
        af[mi] = *(const bf16x8*)((const char*)As + row * 128 + kb);
      }
#pragma unroll
      for (int ni = 0; ni < 4; ++ni) {
        int row = wc * 64 + ni * 16 + fr;
        bfv[ni] = *(const bf16x8*)((const char*)Bs + row * 128 + kb);
      }
#pragma unroll
      for (int mi = 0; mi < 4; ++mi)
#pragma unroll
        for (int ni = 0; ni < 4; ++ni)
          acc[mi][ni] = __builtin_amdgcn_mfma_f32_16x16x32_bf16(af[mi], bfv[ni], acc[mi][ni], 0, 0, 0);
    }
  }
#pragma unroll
  for (int ni = 0; ni < 4; ++ni) {
    const int o = n0 + wc * 64 + ni * 16 + fr;
    const float s = scales[o];
    const float b = bias[o];
#pragma unroll
    for (int mi = 0; mi < 4; ++mi) {
      const int mr = m0 + wr * 64 + mi * 16 + fg * 4;
#pragma unroll
      for (int r = 0; r < 4; ++r)
        out[(size_t)(mr + r) * N_DIM + o] = acc[mi][ni][r] * s + b;
    }
  }
}

extern "C" void kernel_launch(void* const* d_in, const int* in_sizes, int n_in,
                              void* d_out, int out_size, void* d_ws, size_t ws_size,
                              hipStream_t stream) {
  const float* x  = (const float*)d_in[0];
  const int*   wp = (const int*)d_in[1];
  const float* sc = (const float*)d_in[2];
  const float* bs = (const float*)d_in[3];
  float* out = (float*)d_out;

  const size_t a_bytes = (size_t)NTM2 * NKT * 2 * HT_BYTES;  // 33,554,432
  const size_t b_bytes = (size_t)NTN2 * NKT * 2 * HT_BYTES;  // 90,177,536
  unsigned short* wsA = (unsigned short*)d_ws;
  unsigned short* wsB = (unsigned short*)((char*)d_ws + a_bytes);

  if (ws_size >= a_bytes + b_bytes) {
    cvt_x_tiled<<<2048, 256, 0, stream>>>(x, wsA);
    deq_w_tiled<<<2048, 256, 0, stream>>>(wp, wsB);
    qgemm8<<<NBLK2, 512, 0, stream>>>(wsA, wsB, sc, bs, out);
  } else if (ws_size >= a_bytes) {
    cvt_x_kernel<<<2048, 256, 0, stream>>>(x, wsA);
    qgemm_kernel<1><<<NBLK, 256, 0, stream>>>(x, wsA, wp, sc, bs, out);
  } else {
    qgemm_kernel<2><<<NBLK, 256, 0, stream>>>(x, wsA, wp, sc, bs, out);
  }
}

// Round 4
// 439.194 us; speedup vs baseline: 1.4558x; 1.0564x over previous
//
#include <hip/hip_runtime.h>
#include <hip/hip_bf16.h>
#include <stdint.h>

// Problem dims
#define M_DIM 4096      // 2*2048 rows of x
#define K_DIM 4096
#define N_DIM 11008
#define KP    2048      // K/2 packed int32 per w row

// ---------------- 8-phase 256x256 GEMM geometry ----------------
#define BK2   64
#define NKT   (K_DIM/BK2)        // 64 K-tiles
#define NTM2  (M_DIM/256)        // 16
#define NTN2  (N_DIM/256)        // 43
#define NBLK2 (NTM2*NTN2)        // 688  (%8==0 -> bijective XCD swizzle)
#define HT_BYTES 16384           // half-tile: 128 rows x 64 bf16

// ---------------- old 128x128 fallback geometry ----------------
#define BM 128
#define BN 128
#define BK 64
#define NTM (M_DIM/BM)
#define NTN (N_DIM/BN)
#define NBLK (NTM*NTN)

typedef __attribute__((ext_vector_type(8))) short  bf16x8;
typedef __attribute__((ext_vector_type(4))) float  f32x4;
typedef __attribute__((ext_vector_type(8))) unsigned short u16x8;

typedef const void __attribute__((address_space(1)))* gas_ptr;
typedef void __attribute__((address_space(3)))* las_ptr;

__device__ __forceinline__ void async_copy16(void* lds, const void* g) {
  __builtin_amdgcn_global_load_lds((gas_ptr)g, (las_ptr)lds, 16, 0, 0);
}

__device__ __forceinline__ unsigned short f2bf_rne(float f) {
  uint32_t u = __builtin_bit_cast(uint32_t, f);
  u += 0x7FFFu + ((u >> 16) & 1u);
  return (unsigned short)(u >> 16);
}
__device__ __forceinline__ unsigned short i2bf(int v) {
  float f = (float)v;
  return (unsigned short)(__builtin_bit_cast(uint32_t, f) >> 16);
}
__device__ __forceinline__ int sx4(int b, int which) {
  return ((int)((uint32_t)b << (28 - 4 * which))) >> 28;
}
// Bank swizzle: XOR 16B-slot index (bits [6:4]) with row&7 (row = bits [13:7]).
// Verified R3: SQ_LDS_BANK_CONFLICT -> 0. Involution.
__device__ __forceinline__ int swz(int o) { return o ^ (((o >> 7) & 7) << 4); }

// ---------------- pre-pass: tiled + swizzled half-tile images ----------------
// A image: [tm][kt][h] half-tiles of 16KB; within: swz(row*128 + c8*16)
__global__ __launch_bounds__(256) void cvt_x_tiled(const float* __restrict__ x,
                                                   unsigned short* __restrict__ wsA) {
  const int total = NTM2 * NKT * 2 * 1024;   // 16B chunks
  for (int i = blockIdx.x * blockDim.x + threadIdx.x; i < total;
       i += gridDim.x * blockDim.x) {
    int cin = i & 1023;
    int h   = (i >> 10) & 1;
    int kt  = (i >> 11) & 63;
    int tm  = i >> 17;
    int row = cin >> 3, c8 = cin & 7;
    const float* src = x + (size_t)(tm * 256 + h * 128 + row) * K_DIM + kt * 64 + c8 * 8;
    float4 v0 = *(const float4*)src;
    float4 v1 = *(const float4*)(src + 4);
    u16x8 r;
    r[0] = f2bf_rne(v0.x); r[1] = f2bf_rne(v0.y); r[2] = f2bf_rne(v0.z); r[3] = f2bf_rne(v0.w);
    r[4] = f2bf_rne(v1.x); r[5] = f2bf_rne(v1.y); r[6] = f2bf_rne(v1.z); r[7] = f2bf_rne(v1.w);
    *(u16x8*)((char*)wsA + (size_t)(i >> 10) * HT_BYTES + swz(cin * 16)) = r;
  }
}

// B image: [tn][kt][h] half-tiles; dequant int4 nibbles -> exact bf16 q in [-8,7]
__global__ __launch_bounds__(256) void deq_w_tiled(const int* __restrict__ wp,
                                                   unsigned short* __restrict__ wsB) {
  const int total = NTN2 * NKT * 2 * 1024;
  for (int i = blockIdx.x * blockDim.x + threadIdx.x; i < total;
       i += gridDim.x * blockDim.x) {
    int cin = i & 1023;
    int h   = (i >> 10) & 1;
    int kt  = (i >> 11) & 63;
    int tn  = i >> 17;
    int row = cin >> 3, c8 = cin & 7;
    int4 b = *(const int4*)(wp + (size_t)(tn * 256 + h * 128 + row) * KP + kt * 32 + c8 * 4);
    u16x8 r;
    r[0] = i2bf(sx4(b.x, 0)); r[1] = i2bf(sx4(b.x, 1));
    r[2] = i2bf(sx4(b.y, 0)); r[3] = i2bf(sx4(b.y, 1));
    r[4] = i2bf(sx4(b.z, 0)); r[5] = i2bf(sx4(b.z, 1));
    r[6] = i2bf(sx4(b.w, 0)); r[7] = i2bf(sx4(b.w, 1));
    *(u16x8*)((char*)wsB + (size_t)(i >> 10) * HT_BYTES + swz(cin * 16)) = r;
  }
}

// ---------------- 8-phase 256x256 GEMM (MODE 0) ----------------
__global__ __launch_bounds__(512, 2)
void qgemm8(const unsigned short* __restrict__ wsA, const unsigned short* __restrict__ wsB,
            const float* __restrict__ scales, const float* __restrict__ bias,
            float* __restrict__ out) {
  __shared__ __align__(16) char smem[131072];  // 2 buf x (A 32KB + B 32KB)

  const int tid  = threadIdx.x;
  const int lane = tid & 63, wid = tid >> 6;
  const int wr = wid >> 2, wc = wid & 3;       // 2x4 wave grid; per-wave 128x64
  const int fr = lane & 15, fg = lane >> 4;

  int bid = blockIdx.x;
  int id  = (bid & 7) * (NBLK2 / 8) + (bid >> 3);   // bijective XCD chunking
  // tn-major within chunk: 16 consecutive ids share one B panel (concurrent
  // on one XCD -> B L2-resident; B fetched from HBM ~once). A served by L3.
  int tm  = id & (NTM2 - 1), tn = id >> 4;

  const char* gA = (const char*)wsA + (size_t)tm * (NKT * 2) * HT_BYTES;
  const char* gB = (const char*)wsB + (size_t)tn * (NKT * 2) * HT_BYTES;

#define STAGE(ldsoff, src) do { \
    async_copy16(smem + (ldsoff) + (wid * 64) * 16, (src) + (wid * 64 + lane) * 16); \
    async_copy16(smem + (ldsoff) + (512 + wid * 64) * 16, (src) + (512 + wid * 64 + lane) * 16); \
  } while (0)
#define STAGE_A(buf, h, kt) STAGE((buf) * 65536 + (h) * HT_BYTES, gA + ((kt) * 2 + (h)) * HT_BYTES)
#define STAGE_B(buf, h, kt) STAGE((buf) * 65536 + 32768 + (h) * HT_BYTES, gB + ((kt) * 2 + (h)) * HT_BYTES)

  f32x4  acc[8][4] = {};
  bf16x8 aR[4][2];        // one A reg-half (mi 0-3 of sel) x kk
  bf16x8 bR[2][2][2];     // [bn][nl][kk]; B0 stays live through ph3

#define LOAD_A(buf, sel) do { \
    const char* _ab = smem + (buf) * 65536 + wr * HT_BYTES; \
    _Pragma("unroll") for (int i = 0; i < 4; ++i) { \
      int rA = (sel) * 64 + i * 16 + fr; \
      int xr = (rA & 7) << 4; \
      _Pragma("unroll") for (int kk = 0; kk < 2; ++kk) \
        aR[i][kk] = *(const bf16x8*)(_ab + ((rA * 128 + kk * 64 + fg * 16) ^ xr)); \
    } } while (0)
#define LOAD_B(buf, bn) do { \
    const char* _bb = smem + (buf) * 65536 + 32768 + (wc >> 1) * HT_BYTES; \
    _Pragma("unroll") for (int nl = 0; nl < 2; ++nl) { \
      int rB = (wc & 1) * 64 + ((bn) * 2 + nl) * 16 + fr; \
      int xr = (rB & 7) << 4; \
      _Pragma("unroll") for (int kk = 0; kk < 2; ++kk) \
        bR[bn][nl][kk] = *(const bf16x8*)(_bb + ((rB * 128 + kk * 64 + fg * 16) ^ xr)); \
    } } while (0)
#define MMQ(sel, bn) do { \
    _Pragma("unroll") for (int kk = 0; kk < 2; ++kk) \
    _Pragma("unroll") for (int i = 0; i < 4; ++i) \
    _Pragma("unroll") for (int nl = 0; nl < 2; ++nl) \
      acc[(sel) * 4 + i][(bn) * 2 + nl] = __builtin_amdgcn_mfma_f32_16x16x32_bf16( \
          aR[i][kk], bR[bn][nl][kk], acc[(sel) * 4 + i][(bn) * 2 + nl], 0, 0, 0); \
  } while (0)

// bare s_barrier (no sched_barrier: m141 order-pinning costs ~40%)
#define PH_BAR __builtin_amdgcn_s_barrier()
#define LGKM0 asm volatile("s_waitcnt lgkmcnt(0)" ::: "memory")
#define VMC4  asm volatile("s_waitcnt vmcnt(4)" ::: "memory")
#define PRIO1 __builtin_amdgcn_s_setprio(1)
#define PRIO0 __builtin_amdgcn_s_setprio(0)

  // Prologue: buf0 <- tile0 (B0,B1,A0,A1), buf1 <- tile1 (B0,B1). 12 loads.
  STAGE_B(0, 0, 0); STAGE_B(0, 1, 0);
  STAGE_A(0, 0, 0); STAGE_A(0, 1, 0);
  STAGE_B(1, 0, 1); STAGE_B(1, 1, 1);
  VMC4;        // drain buf0's 8 loads, keep buf1's 4
  PH_BAR;

  for (int t = 0; t < NKT / 2; ++t) {
    const int k1 = 2 * t + 1;
    const int k2 = (2 * t + 2 < NKT) ? 2 * t + 2 : NKT - 1;  // tail clamp (never read)
    const int k3 = (2 * t + 3 < NKT) ? 2 * t + 3 : NKT - 1;

    // ---- ph0: Q(A0,B0) of buf0 ----
    LOAD_A(0, 0); LOAD_B(0, 0);
    STAGE_A(1, 0, k1);
    PH_BAR; LGKM0;
    PRIO1; MMQ(0, 0); PRIO0;
    PH_BAR;
    // ---- ph1: Q(A0,B1) ----
    LOAD_B(0, 1);
    STAGE_A(1, 1, k1);
    PH_BAR; LGKM0;
    PRIO1; MMQ(0, 1); PRIO0;
    PH_BAR;
    // ---- ph2: Q(A1,B1) ----
    LOAD_A(0, 1);
    STAGE_B(0, 0, k2);          // buf0.B freed after ph1
    PH_BAR; LGKM0;
    PRIO1; MMQ(1, 1); PRIO0;
    PH_BAR;
    // ---- ph3: Q(A1,B0) from regs; guard buf1 for ph4-7 ----
    STAGE_B(0, 1, k2);
    VMC4;                        // drain through buf1.A-h1 (ph1 of this iter)
    PH_BAR;
    PRIO1; MMQ(1, 0); PRIO0;
    PH_BAR;
    // ---- ph4: Q(A0,B0) of buf1 ----
    LOAD_A(1, 0); LOAD_B(1, 0);
    STAGE_A(0, 0, k2);           // buf0.A freed after ph2
    PH_BAR; LGKM0;
    PRIO1; MMQ(0, 0); PRIO0;
    PH_BAR;
    // ---- ph5: Q(A0,B1) ----
    LOAD_B(1, 1);
    STAGE_A(0, 1, k2);
    PH_BAR; LGKM0;
    PRIO1; MMQ(0, 1); PRIO0;
    PH_BAR;
    // ---- ph6: Q(A1,B1) ----
    LOAD_A(1, 1);
    STAGE_B(1, 0, k3);           // buf1.B freed after ph5
    PH_BAR; LGKM0;
    PRIO1; MMQ(1, 1); PRIO0;
    PH_BAR;
    // ---- ph7: Q(A1,B0) from regs; guard buf0 for next ph0-3 ----
    STAGE_B(1, 1, k3);
    VMC4;                        // drain through buf0.A-h1 (ph5 of this iter)
    PH_BAR;
    PRIO1; MMQ(1, 0); PRIO0;
    PH_BAR;
  }

  // ---- epilogue: y = acc*scale + bias; C layout col=lane&15, row=fg*4+reg ----
  // nontemporal stores: don't evict B/A panels from L2/L3 with the 180MB out stream
  const int m0 = tm * 256, n0 = tn * 256;
#pragma unroll
  for (int ni = 0; ni < 4; ++ni) {
    const int o = n0 + wc * 64 + ni * 16 + fr;
    const float s = scales[o];
    const float b = bias[o];
#pragma unroll
    for (int mi = 0; mi < 8; ++mi) {
      const int mr = m0 + wr * 128 + mi * 16 + fg * 4;
#pragma unroll
      for (int r = 0; r < 4; ++r)
        __builtin_nontemporal_store(acc[mi][ni][r] * s + b,
                                    out + (size_t)(mr + r) * N_DIM + o);
    }
  }
#undef STAGE
#undef STAGE_A
#undef STAGE_B
#undef LOAD_A
#undef LOAD_B
#undef MMQ
#undef PH_BAR
#undef LGKM0
#undef VMC4
#undef PRIO1
#undef PRIO0
}

// ---------------- fallback pre-pass (linear xb) + 128x128 GEMM ----------------
__global__ __launch_bounds__(256) void cvt_x_kernel(const float* __restrict__ x,
                                                    unsigned short* __restrict__ xb) {
  const int n4 = M_DIM * K_DIM / 4;
  int i = blockIdx.x * blockDim.x + threadIdx.x;
  const int stride = gridDim.x * blockDim.x;
  for (; i < n4; i += stride) {
    float4 v = ((const float4*)x)[i];
    ushort4 r;
    r.x = f2bf_rne(v.x); r.y = f2bf_rne(v.y);
    r.z = f2bf_rne(v.z); r.w = f2bf_rne(v.w);
    ((ushort4*)xb)[i] = r;
  }
}

template <int MODE>
__global__ __launch_bounds__(256)
void qgemm_kernel(const float* __restrict__ x, const unsigned short* __restrict__ xb,
                  const int* __restrict__ wp,
                  const float* __restrict__ scales, const float* __restrict__ bias,
                  float* __restrict__ out) {
  __shared__ __align__(16) unsigned short As[BM * BK];
  __shared__ __align__(16) unsigned short Bs[BN * BK];
  const int tid  = threadIdx.x;
  const int lane = tid & 63;
  const int wid  = tid >> 6;
  int bid = blockIdx.x;
  int swzb = (bid & 7) * (NBLK / 8) + (bid >> 3);
  const int tm = swzb & (NTM - 1);
  const int tn = swzb >> 5;
  const int m0 = tm * BM, n0 = tn * BN;
  const int wr = wid >> 1, wc = wid & 1;
  const int fr = lane & 15;
  const int fg = lane >> 4;
  f32x4 acc[4][4] = {};

  for (int kt = 0; kt < K_DIM / BK; ++kt) {
    int4   breg[4];
    float4 areg[8];
#pragma unroll
    for (int p = 0; p < 4; ++p) {
      int fl = p * 256 + tid;
      int row = fl >> 3, u = fl & 7;
      breg[p] = *(const int4*)(wp + (size_t)(n0 + row) * KP + kt * (BK / 2) + u * 4);
    }
    if constexpr (MODE == 2) {
#pragma unroll
      for (int p = 0; p < 8; ++p) {
        int fl = p * 256 + tid;
        int row = fl >> 4, u = fl & 15;
        areg[p] = *(const float4*)(x + (size_t)(m0 + row) * K_DIM + kt * BK + u * 4);
      }
    }
    __syncthreads();
    if constexpr (MODE == 1) {
#pragma unroll
      for (int p = 0; p < 4; ++p) {
        int t16 = p * 256 + tid;
        int row = t16 >> 3, u = t16 & 7;
        const unsigned short* g = xb + (size_t)(m0 + row) * K_DIM + kt * BK + u * 8;
        async_copy16((char*)As + (p * 256 + wid * 64) * 16, g);
      }
    } else {
#pragma unroll
      for (int p = 0; p < 8; ++p) {
        int fl = p * 256 + tid;
        int row = fl >> 4, u = fl & 15;
        ushort4 r;
        r.x = f2bf_rne(areg[p].x); r.y = f2bf_rne(areg[p].y);
        r.z = f2bf_rne(areg[p].z); r.w = f2bf_rne(areg[p].w);
        *(ushort4*)((char*)As + row * 128 + u * 8) = r;
      }
    }
#pragma unroll
    for (int p = 0; p < 4; ++p) {
      int fl = p * 256 + tid;
      int row = fl >> 3, u = fl & 7;
      int4 b = breg[p];
      u16x8 r;
      r[0] = i2bf(sx4(b.x, 0)); r[1] = i2bf(sx4(b.x, 1));
      r[2] = i2bf(sx4(b.y, 0)); r[3] = i2bf(sx4(b.y, 1));
      r[4] = i2bf(sx4(b.z, 0)); r[5] = i2bf(sx4(b.z, 1));
      r[6] = i2bf(sx4(b.w, 0)); r[7] = i2bf(sx4(b.w, 1));
      *(u16x8*)((char*)Bs + row * 128 + u * 16) = r;
    }
    __syncthreads();
#pragma unroll
    for (int kk = 0; kk < 2; ++kk) {
      const int kb = kk * 64 + fg * 16;
      bf16x8 af[4], bfv[4];
#pragma unroll
      for (int mi = 0; mi < 4; ++mi) {
        int row = wr * 64 + mi * 16 + fr;
        af[mi] = *(const bf16x8*)((const char*)As + row * 128 + kb);
      }
#pragma unroll
      for (int ni = 0; ni < 4; ++ni) {
        int row = wc * 64 + ni * 16 + fr;
        bfv[ni] = *(const bf16x8*)((const char*)Bs + row * 128 + kb);
      }
#pragma unroll
      for (int mi = 0; mi < 4; ++mi)
#pragma unroll
        for (int ni = 0; ni < 4; ++ni)
          acc[mi][ni] = __builtin_amdgcn_mfma_f32_16x16x32_bf16(af[mi], bfv[ni], acc[mi][ni], 0, 0, 0);
    }
  }
#pragma unroll
  for (int ni = 0; ni < 4; ++ni) {
    const int o = n0 + wc * 64 + ni * 16 + fr;
    const float s = scales[o];
    const float b = bias[o];
#pragma unroll
    for (int mi = 0; mi < 4; ++mi) {
      const int mr = m0 + wr * 64 + mi * 16 + fg * 4;
#pragma unroll
      for (int r = 0; r < 4; ++r)
        out[(size_t)(mr + r) * N_DIM + o] = acc[mi][ni][r] * s + b;
    }
  }
}

extern "C" void kernel_launch(void* const* d_in, const int* in_sizes, int n_in,
                              void* d_out, int out_size, void* d_ws, size_t ws_size,
                              hipStream_t stream) {
  const float* x  = (const float*)d_in[0];
  const int*   wp = (const int*)d_in[1];
  const float* sc = (const float*)d_in[2];
  const float* bs = (const float*)d_in[3];
  float* out = (float*)d_out;

  const size_t a_bytes = (size_t)NTM2 * NKT * 2 * HT_BYTES;  // 33,554,432
  const size_t b_bytes = (size_t)NTN2 * NKT * 2 * HT_BYTES;  // 90,177,536
  unsigned short* wsA = (unsigned short*)d_ws;
  unsigned short* wsB = (unsigned short*)((char*)d_ws + a_bytes);

  if (ws_size >= a_bytes + b_bytes) {
    cvt_x_tiled<<<2048, 256, 0, stream>>>(x, wsA);
    deq_w_tiled<<<2048, 256, 0, stream>>>(wp, wsB);
    qgemm8<<<NBLK2, 512, 0, stream>>>(wsA, wsB, sc, bs, out);
  } else if (ws_size >= a_bytes) {
    cvt_x_kernel<<<2048, 256, 0, stream>>>(x, wsA);
    qgemm_kernel<1><<<NBLK, 256, 0, stream>>>(x, wsA, wp, sc, bs, out);
  } else {
    qgemm_kernel<2><<<NBLK, 256, 0, stream>>>(x, wsA, wp, sc, bs, out);
  }
}

// Round 5
// 399.854 us; speedup vs baseline: 1.5990x; 1.0984x over previous
//
#include <hip/hip_runtime.h>
#include <hip/hip_bf16.h>
#include <stdint.h>

// Problem dims
#define M_DIM 4096      // 2*2048 rows of x
#define K_DIM 4096
#define N_DIM 11008
#define KP    2048      // K/2 packed int32 per w row

// ---------------- 8-phase 256x256 GEMM geometry ----------------
#define BK2   64
#define NKT   (K_DIM/BK2)        // 64 K-tiles
#define NTM2  (M_DIM/256)        // 16
#define NTN2  (N_DIM/256)        // 43
#define NBLK2 (NTM2*NTN2)        // 688  (%8==0 -> bijective XCD swizzle)
#define HT_BYTES 16384           // half-tile: 128 rows x 64 bf16

// ---------------- 128x128 fallback geometry ----------------
#define BM 128
#define BN 128
#define BK 64
#define NTM (M_DIM/BM)
#define NTN (N_DIM/BN)
#define NBLK (NTM*NTN)

typedef __attribute__((ext_vector_type(8)))  short bf16x8;
typedef __attribute__((ext_vector_type(4)))  float f32x4;
typedef __attribute__((ext_vector_type(16))) float f32x16;
typedef __attribute__((ext_vector_type(8)))  unsigned short u16x8;

typedef const void __attribute__((address_space(1)))* gas_ptr;
typedef void __attribute__((address_space(3)))* las_ptr;

__device__ __forceinline__ void async_copy16(void* lds, const void* g) {
  __builtin_amdgcn_global_load_lds((gas_ptr)g, (las_ptr)lds, 16, 0, 0);
}

__device__ __forceinline__ unsigned short f2bf_rne(float f) {
  uint32_t u = __builtin_bit_cast(uint32_t, f);
  u += 0x7FFFu + ((u >> 16) & 1u);
  return (unsigned short)(u >> 16);
}
__device__ __forceinline__ unsigned short i2bf(int v) {
  float f = (float)v;
  return (unsigned short)(__builtin_bit_cast(uint32_t, f) >> 16);
}
__device__ __forceinline__ int sx4(int b, int which) {
  return ((int)((uint32_t)b << (28 - 4 * which))) >> 28;
}
// Bank swizzle: XOR 16B-slot index (bits [6:4]) with row&7 (row = bits [13:7]).
// Verified R3: SQ_LDS_BANK_CONFLICT -> 0. Involution.
__device__ __forceinline__ int swz(int o) { return o ^ (((o >> 7) & 7) << 4); }

// ---------------- pre-pass: tiled + swizzled half-tile images ----------------
__global__ __launch_bounds__(256) void cvt_x_tiled(const float* __restrict__ x,
                                                   unsigned short* __restrict__ wsA) {
  const int total = NTM2 * NKT * 2 * 1024;   // 16B chunks
  for (int i = blockIdx.x * blockDim.x + threadIdx.x; i < total;
       i += gridDim.x * blockDim.x) {
    int cin = i & 1023;
    int h   = (i >> 10) & 1;
    int kt  = (i >> 11) & 63;
    int tm  = i >> 17;
    int row = cin >> 3, c8 = cin & 7;
    const float* src = x + (size_t)(tm * 256 + h * 128 + row) * K_DIM + kt * 64 + c8 * 8;
    float4 v0 = *(const float4*)src;
    float4 v1 = *(const float4*)(src + 4);
    u16x8 r;
    r[0] = f2bf_rne(v0.x); r[1] = f2bf_rne(v0.y); r[2] = f2bf_rne(v0.z); r[3] = f2bf_rne(v0.w);
    r[4] = f2bf_rne(v1.x); r[5] = f2bf_rne(v1.y); r[6] = f2bf_rne(v1.z); r[7] = f2bf_rne(v1.w);
    *(u16x8*)((char*)wsA + (size_t)(i >> 10) * HT_BYTES + swz(cin * 16)) = r;
  }
}

__global__ __launch_bounds__(256) void deq_w_tiled(const int* __restrict__ wp,
                                                   unsigned short* __restrict__ wsB) {
  const int total = NTN2 * NKT * 2 * 1024;
  for (int i = blockIdx.x * blockDim.x + threadIdx.x; i < total;
       i += gridDim.x * blockDim.x) {
    int cin = i & 1023;
    int h   = (i >> 10) & 1;
    int kt  = (i >> 11) & 63;
    int tn  = i >> 17;
    int row = cin >> 3, c8 = cin & 7;
    int4 b = *(const int4*)(wp + (size_t)(tn * 256 + h * 128 + row) * KP + kt * 32 + c8 * 4);
    u16x8 r;
    r[0] = i2bf(sx4(b.x, 0)); r[1] = i2bf(sx4(b.x, 1));
    r[2] = i2bf(sx4(b.y, 0)); r[3] = i2bf(sx4(b.y, 1));
    r[4] = i2bf(sx4(b.z, 0)); r[5] = i2bf(sx4(b.z, 1));
    r[6] = i2bf(sx4(b.w, 0)); r[7] = i2bf(sx4(b.w, 1));
    *(u16x8*)((char*)wsB + (size_t)(i >> 10) * HT_BYTES + swz(cin * 16)) = r;
  }
}

// ---------------- 8-phase 256x256 GEMM, 32x32x16, pipelined loads ----------------
__global__ __launch_bounds__(512, 2)
void qgemm8(const unsigned short* __restrict__ wsA, const unsigned short* __restrict__ wsB,
            const float* __restrict__ scales, const float* __restrict__ bias,
            float* __restrict__ out) {
  __shared__ __align__(16) char smem[131072];  // 2 buf x (A 32KB + B 32KB)

  const int tid  = threadIdx.x;
  const int lane = tid & 63, wid = tid >> 6;
  const int wr = wid >> 2, wc = wid & 3;       // 2x4 wave grid; per-wave 128x64
  const int l31 = lane & 31, kg = lane >> 5;   // 32x32 operand: row=lane&31, k-grp=lane>>5

  int bid = blockIdx.x;
  int id  = (bid & 7) * (NBLK2 / 8) + (bid >> 3);   // bijective XCD chunking
  int tm  = id & (NTM2 - 1), tn = id >> 4;          // tn-major: B panel shared per XCD

  const char* gA = (const char*)wsA + (size_t)tm * (NKT * 2) * HT_BYTES;
  const char* gB = (const char*)wsB + (size_t)tn * (NKT * 2) * HT_BYTES;

#define STAGE(ldsoff, src) do { \
    async_copy16(smem + (ldsoff) + (wid * 64) * 16, (src) + (wid * 64 + lane) * 16); \
    async_copy16(smem + (ldsoff) + (512 + wid * 64) * 16, (src) + (512 + wid * 64 + lane) * 16); \
  } while (0)
#define STAGE_A(buf, h, kt) STAGE((buf) * 65536 + (h) * HT_BYTES, gA + ((kt) * 2 + (h)) * HT_BYTES)
#define STAGE_B(buf, h, kt) STAGE((buf) * 65536 + 32768 + (h) * HT_BYTES, gB + ((kt) * 2 + (h)) * HT_BYTES)

  f32x16 acc[4][2] = {};   // [msub 0..3][nsub 0..1], 128 regs
  bf16x8 aS0[2][4], aS1[2][4];   // A frag sets: [msub-in-pair][kstep]
  bf16x8 bS0[4], bS1[4];         // B frag sets: [kstep]

  // A frags: row = msub*32 + l31 (within wave's wr-half); col = ks*32 + kg*16
#define LDA_SET(dst, buf, sel) do { \
    const char* _ab = smem + (buf) * 65536 + wr * HT_BYTES; \
    _Pragma("unroll") for (int i = 0; i < 2; ++i) { \
      int row = ((sel) * 2 + i) * 32 + l31; \
      int xr = (row & 7) << 4; \
      int base = row * 128; \
      _Pragma("unroll") for (int ks = 0; ks < 4; ++ks) \
        dst[i][ks] = *(const bf16x8*)(_ab + base + ((ks * 32 + kg * 16) ^ xr)); \
    } } while (0)
#define LDB_SET(dst, buf, bn) do { \
    const char* _bb = smem + (buf) * 65536 + 32768 + (wc >> 1) * HT_BYTES; \
    { int row = (wc & 1) * 64 + (bn) * 32 + l31; \
      int xr = (row & 7) << 4; \
      int base = row * 128; \
      _Pragma("unroll") for (int ks = 0; ks < 4; ++ks) \
        dst[ks] = *(const bf16x8*)(_bb + base + ((ks * 32 + kg * 16) ^ xr)); \
    } } while (0)
#define MMQ(aS, bS, sel, bn) do { \
    _Pragma("unroll") for (int ks = 0; ks < 4; ++ks) \
    _Pragma("unroll") for (int i = 0; i < 2; ++i) \
      acc[(sel) * 2 + i][bn] = __builtin_amdgcn_mfma_f32_32x32x16_bf16( \
          aS[i][ks], bS[ks], acc[(sel) * 2 + i][bn], 0, 0, 0); \
  } while (0)

#define PH_BAR __builtin_amdgcn_s_barrier()
#define LGKM0 asm volatile("s_waitcnt lgkmcnt(0)" ::: "memory")
#define VMC2  asm volatile("s_waitcnt vmcnt(2)" ::: "memory")
#define VMC4  asm volatile("s_waitcnt vmcnt(4)" ::: "memory")
#define PRIO1 __builtin_amdgcn_s_setprio(1)
#define PRIO0 __builtin_amdgcn_s_setprio(0)

  // Prologue: buf0 <- tile0 (8 loads), buf1.B <- tile1 (4 loads).
  STAGE_B(0, 0, 0); STAGE_B(0, 1, 0);
  STAGE_A(0, 0, 0); STAGE_A(0, 1, 0);
  STAGE_B(1, 0, 1); STAGE_B(1, 1, 1);
  VMC4;        // drain buf0's 8, keep buf1.B's 4 in flight
  PH_BAR;
  LDA_SET(aS0, 0, 0); LDB_SET(bS0, 0, 0);   // operands for ph0

  for (int t = 0; t < NKT / 2; ++t) {
    const int k1 = 2 * t + 1;
    const int k2 = (2 * t + 2 < NKT) ? 2 * t + 2 : NKT - 1;  // tail clamp (never read)
    const int k3 = (2 * t + 3 < NKT) ? 2 * t + 3 : NKT - 1;

    // ph0: Q(A0,B0)@buf0 ; prefetch bS1
    LGKM0; PRIO1; MMQ(aS0, bS0, 0, 0); PRIO0;
    STAGE_A(1, 0, k1);
    LDB_SET(bS1, 0, 1);
    PH_BAR;
    // ph1: Q(A0,B1) ; prefetch aS1
    LGKM0; PRIO1; MMQ(aS0, bS1, 0, 1); PRIO0;
    STAGE_A(1, 1, k1);
    LDA_SET(aS1, 0, 1);
    PH_BAR;
    // ph2: Q(A1,B1) ; drain buf1.A(k1)+buf1.B(k1)
    LGKM0; PRIO1; MMQ(aS1, bS1, 1, 1); PRIO0;
    STAGE_B(0, 0, k2);
    VMC2;
    PH_BAR;
    // ph3: Q(A1,B0) ; prefetch buf1 operands (aS0, bS0)
    PRIO1; MMQ(aS1, bS0, 1, 0); PRIO0;
    STAGE_B(0, 1, k2);
    LDA_SET(aS0, 1, 0); LDB_SET(bS0, 1, 0);
    PH_BAR;
    // ph4: Q(A0,B0)@buf1
    LGKM0; PRIO1; MMQ(aS0, bS0, 0, 0); PRIO0;
    STAGE_A(0, 0, k2);
    LDB_SET(bS1, 1, 1);
    PH_BAR;
    // ph5: Q(A0,B1)
    LGKM0; PRIO1; MMQ(aS0, bS1, 0, 1); PRIO0;
    STAGE_A(0, 1, k2);
    LDA_SET(aS1, 1, 1);
    PH_BAR;
    // ph6: Q(A1,B1) ; drain buf0.B(k2)+buf0.A(k2)
    LGKM0; PRIO1; MMQ(aS1, bS1, 1, 1); PRIO0;
    STAGE_B(1, 0, k3);
    VMC2;
    PH_BAR;
    // ph7: Q(A1,B0) ; prefetch buf0 operands for next iter
    PRIO1; MMQ(aS1, bS0, 1, 0); PRIO0;
    STAGE_B(1, 1, k3);
    LDA_SET(aS0, 0, 0); LDB_SET(bS0, 0, 0);
    PH_BAR;
  }

  // ---- epilogue: y = acc*scale + bias ----
  // 32x32 C/D (m74/m101): col = lane&31, row = (reg&3) + 8*(reg>>2) + 4*(lane>>5)
  const int m0 = tm * 256, n0 = tn * 256;
#pragma unroll
  for (int ni = 0; ni < 2; ++ni) {
    const int o = n0 + wc * 64 + ni * 32 + l31;
    const float s = scales[o];
    const float b = bias[o];
#pragma unroll
    for (int mi = 0; mi < 4; ++mi) {
      const int mrb = m0 + wr * 128 + mi * 32 + kg * 4;
#pragma unroll
      for (int r = 0; r < 16; ++r) {
        const int mr = mrb + (r & 3) + 8 * (r >> 2);
        __builtin_nontemporal_store(acc[mi][ni][r] * s + b,
                                    out + (size_t)mr * N_DIM + o);
      }
    }
  }
#undef STAGE
#undef STAGE_A
#undef STAGE_B
#undef LDA_SET
#undef LDB_SET
#undef MMQ
#undef PH_BAR
#undef LGKM0
#undef VMC2
#undef VMC4
#undef PRIO1
#undef PRIO0
}

// ---------------- fallback pre-pass (linear xb) + 128x128 GEMM ----------------
__global__ __launch_bounds__(256) void cvt_x_kernel(const float* __restrict__ x,
                                                    unsigned short* __restrict__ xb) {
  const int n4 = M_DIM * K_DIM / 4;
  int i = blockIdx.x * blockDim.x + threadIdx.x;
  const int stride = gridDim.x * blockDim.x;
  for (; i < n4; i += stride) {
    float4 v = ((const float4*)x)[i];
    ushort4 r;
    r.x = f2bf_rne(v.x); r.y = f2bf_rne(v.y);
    r.z = f2bf_rne(v.z); r.w = f2bf_rne(v.w);
    ((ushort4*)xb)[i] = r;
  }
}

template <int MODE>
__global__ __launch_bounds__(256)
void qgemm_kernel(const float* __restrict__ x, const unsigned short* __restrict__ xb,
                  const int* __restrict__ wp,
                  const float* __restrict__ scales, const float* __restrict__ bias,
                  float* __restrict__ out) {
  __shared__ __align__(16) unsigned short As[BM * BK];
  __shared__ __align__(16) unsigned short Bs[BN * BK];
  const int tid  = threadIdx.x;
  const int lane = tid & 63;
  const int wid  = tid >> 6;
  int bid = blockIdx.x;
  int swzb = (bid & 7) * (NBLK / 8) + (bid >> 3);
  const int tm = swzb & (NTM - 1);
  const int tn = swzb >> 5;
  const int m0 = tm * BM, n0 = tn * BN;
  const int wr = wid >> 1, wc = wid & 1;
  const int fr = lane & 15;
  const int fg = lane >> 4;
  f32x4 acc[4][4] = {};

  for (int kt = 0; kt < K_DIM / BK; ++kt) {
    int4   breg[4];
    float4 areg[8];
#pragma unroll
    for (int p = 0; p < 4; ++p) {
      int fl = p * 256 + tid;
      int row = fl >> 3, u = fl & 7;
      breg[p] = *(const int4*)(wp + (size_t)(n0 + row) * KP + kt * (BK / 2) + u * 4);
    }
    if constexpr (MODE == 2) {
#pragma unroll
      for (int p = 0; p < 8; ++p) {
        int fl = p * 256 + tid;
        int row = fl >> 4, u = fl & 15;
        areg[p] = *(const float4*)(x + (size_t)(m0 + row) * K_DIM + kt * BK + u * 4);
      }
    }
    __syncthreads();
    if constexpr (MODE == 1) {
#pragma unroll
      for (int p = 0; p < 4; ++p) {
        int t16 = p * 256 + tid;
        int row = t16 >> 3, u = t16 & 7;
        const unsigned short* g = xb + (size_t)(m0 + row) * K_DIM + kt * BK + u * 8;
        async_copy16((char*)As + (p * 256 + wid * 64) * 16, g);
      }
    } else {
#pragma unroll
      for (int p = 0; p < 8; ++p) {
        int fl = p * 256 + tid;
        int row = fl >> 4, u = fl & 15;
        ushort4 r;
        r.x = f2bf_rne(areg[p].x); r.y = f2bf_rne(areg[p].y);
        r.z = f2bf_rne(areg[p].z); r.w = f2bf_rne(areg[p].w);
        *(ushort4*)((char*)As + row * 128 + u * 8) = r;
      }
    }
#pragma unroll
    for (int p = 0; p < 4; ++p) {
      int fl = p * 256 + tid;
      int row = fl >> 3, u = fl & 7;
      int4 b = breg[p];
      u16x8 r;
      r[0] = i2bf(sx4(b.x, 0)); r[1] = i2bf(sx4(b.x, 1));
      r[2] = i2bf(sx4(b.y, 0)); r[3] = i2bf(sx4(b.y, 1));
      r[4] = i2bf(sx4(b.z, 0)); r[5] = i2bf(sx4(b.z, 1));
      r[6] = i2bf(sx4(b.w, 0)); r[7] = i2bf(sx4(b.w, 1));
      *(u16x8*)((char*)Bs + row * 128 + u * 16) = r;
    }
    __syncthreads();
#pragma unroll
    for (int kk = 0; kk < 2; ++kk) {
      const int kb = kk * 64 + fg * 16;
      bf16x8 af[4], bfv[4];
#pragma unroll
      for (int mi = 0; mi < 4; ++mi) {
        int row = wr * 64 + mi * 16 + fr;
        af[mi] = *(const bf16x8*)((const char*)As + row * 128 + kb);
      }
#pragma unroll
      for (int ni = 0; ni < 4; ++ni) {
        int row = wc * 64 + ni * 16 + fr;
        bfv[ni] = *(const bf16x8*)((const char*)Bs + row * 128 + kb);
      }
#pragma unroll
      for (int mi = 0; mi < 4; ++mi)
#pragma unroll
        for (int ni = 0; ni < 4; ++ni)
          acc[mi][ni] = __builtin_amdgcn_mfma_f32_16x16x32_bf16(af[mi], bfv[ni], acc[mi][ni], 0, 0, 0);
    }
  }
#pragma unroll
  for (int ni = 0; ni < 4; ++ni) {
    const int o = n0 + wc * 64 + ni * 16 + fr;
    const float s = scales[o];
    const float b = bias[o];
#pragma unroll
    for (int mi = 0; mi < 4; ++mi) {
      const int mr = m0 + wr * 64 + mi * 16 + fg * 4;
#pragma unroll
      for (int r = 0; r < 4; ++r)
        out[(size_t)(mr + r) * N_DIM + o] = acc[mi][ni][r] * s + b;
    }
  }
}

extern "C" void kernel_launch(void* const* d_in, const int* in_sizes, int n_in,
                              void* d_out, int out_size, void* d_ws, size_t ws_size,
                              hipStream_t stream) {
  const float* x  = (const float*)d_in[0];
  const int*   wp = (const int*)d_in[1];
  const float* sc = (const float*)d_in[2];
  const float* bs = (const float*)d_in[3];
  float* out = (float*)d_out;

  const size_t a_bytes = (size_t)NTM2 * NKT * 2 * HT_BYTES;  // 33,554,432
  const size_t b_bytes = (size_t)NTN2 * NKT * 2 * HT_BYTES;  // 90,177,536
  unsigned short* wsA = (unsigned short*)d_ws;
  unsigned short* wsB = (unsigned short*)((char*)d_ws + a_bytes);

  if (ws_size >= a_bytes + b_bytes) {
    cvt_x_tiled<<<2048, 256, 0, stream>>>(x, wsA);
    deq_w_tiled<<<2048, 256, 0, stream>>>(wp, wsB);
    qgemm8<<<NBLK2, 512, 0, stream>>>(wsA, wsB, sc, bs, out);
  } else if (ws_size >= a_bytes) {
    cvt_x_kernel<<<2048, 256, 0, stream>>>(x, wsA);
    qgemm_kernel<1><<<NBLK, 256, 0, stream>>>(x, wsA, wp, sc, bs, out);
  } else {
    qgemm_kernel<2><<<NBLK, 256, 0, stream>>>(x, wsA, wp, sc, bs, out);
  }
}

// Round 6
// 375.951 us; speedup vs baseline: 1.7006x; 1.0636x over previous
//
#include <hip/hip_runtime.h>
#include <hip/hip_bf16.h>
#include <stdint.h>

// Problem dims
#define M_DIM 4096      // 2*2048 rows of x
#define K_DIM 4096
#define N_DIM 11008
#define KP    2048      // K/2 packed int32 per w row

// ---------------- 8-phase 256x256 GEMM geometry ----------------
#define BK2   64
#define NKT   (K_DIM/BK2)        // 64 K-tiles
#define NTM2  (M_DIM/256)        // 16
#define NTN2  (N_DIM/256)        // 43
#define NBLK2 (NTM2*NTN2)        // 688  (%8==0 -> bijective XCD swizzle)
#define HT_BYTES 16384           // half-tile: 128 rows x 64 bf16 (fragment-major)

// ---------------- 128x128 fallback geometry ----------------
#define BM 128
#define BN 128
#define BK 64
#define NTM (M_DIM/BM)
#define NTN (N_DIM/BN)
#define NBLK (NTM*NTN)

typedef __attribute__((ext_vector_type(8)))  short bf16x8;
typedef __attribute__((ext_vector_type(4)))  float f32x4;
typedef __attribute__((ext_vector_type(16))) float f32x16;
typedef __attribute__((ext_vector_type(8)))  unsigned short u16x8;

typedef const void __attribute__((address_space(1)))* gas_ptr;
typedef void __attribute__((address_space(3)))* las_ptr;

__device__ __forceinline__ void async_copy16(void* lds, const void* g) {
  __builtin_amdgcn_global_load_lds((gas_ptr)g, (las_ptr)lds, 16, 0, 0);
}

__device__ __forceinline__ unsigned short f2bf_rne(float f) {
  uint32_t u = __builtin_bit_cast(uint32_t, f);
  u += 0x7FFFu + ((u >> 16) & 1u);
  return (unsigned short)(u >> 16);
}
__device__ __forceinline__ unsigned short i2bf(int v) {
  float f = (float)v;
  return (unsigned short)(__builtin_bit_cast(uint32_t, f) >> 16);
}
__device__ __forceinline__ int sx4(int b, int which) {
  return ((int)((uint32_t)b << (28 - 4 * which))) >> 28;
}

// ---------------- pre-pass: fragment-major half-tile images ----------------
// Half-tile image (16KB = 1024 x 16B chunks): chunk c = msub*256 + ks*64 + kg*32 + l31
// holds T[msub*32 + l31][ks*16 + kg*8 .. +8]  (T = 128-row x 64-col bf16 tile).
// A wave's MFMA fragment read (fixed msub,ks) = 64 lanes x 16B CONTIGUOUS -> 0 conflicts.

__global__ __launch_bounds__(256) void cvt_x_tiled(const float* __restrict__ x,
                                                   unsigned short* __restrict__ wsA) {
  const int total = NTM2 * NKT * 2 * 1024;   // 16B chunks, source-ordered
  for (int i = blockIdx.x * blockDim.x + threadIdx.x; i < total;
       i += gridDim.x * blockDim.x) {
    int rc  = i & 1023;            // source chunk within half-tile
    int h   = (i >> 10) & 1;
    int kt  = (i >> 11) & 63;
    int tm  = i >> 17;
    int row = rc >> 3, e8 = rc & 7;         // 8 consecutive f32 per chunk (coalesced)
    const float* src = x + (size_t)(tm * 256 + h * 128 + row) * K_DIM + kt * 64 + e8 * 8;
    float4 v0 = *(const float4*)src;
    float4 v1 = *(const float4*)(src + 4);
    u16x8 r;
    r[0] = f2bf_rne(v0.x); r[1] = f2bf_rne(v0.y); r[2] = f2bf_rne(v0.z); r[3] = f2bf_rne(v0.w);
    r[4] = f2bf_rne(v1.x); r[5] = f2bf_rne(v1.y); r[6] = f2bf_rne(v1.z); r[7] = f2bf_rne(v1.w);
    int c = (row >> 5) * 256 + (e8 >> 1) * 64 + (e8 & 1) * 32 + (row & 31);
    *(u16x8*)((char*)wsA + (size_t)(i >> 10) * HT_BYTES + c * 16) = r;
  }
}

__global__ __launch_bounds__(256) void deq_w_tiled(const int* __restrict__ wp,
                                                   unsigned short* __restrict__ wsB) {
  const int total = NTN2 * NKT * 2 * 1024;
  for (int i = blockIdx.x * blockDim.x + threadIdx.x; i < total;
       i += gridDim.x * blockDim.x) {
    int rc  = i & 1023;
    int h   = (i >> 10) & 1;
    int kt  = (i >> 11) & 63;
    int tn  = i >> 17;
    int row = rc >> 3, e8 = rc & 7;
    int4 b = *(const int4*)(wp + (size_t)(tn * 256 + h * 128 + row) * KP + kt * 32 + e8 * 4);
    u16x8 r;
    r[0] = i2bf(sx4(b.x, 0)); r[1] = i2bf(sx4(b.x, 1));
    r[2] = i2bf(sx4(b.y, 0)); r[3] = i2bf(sx4(b.y, 1));
    r[4] = i2bf(sx4(b.z, 0)); r[5] = i2bf(sx4(b.z, 1));
    r[6] = i2bf(sx4(b.w, 0)); r[7] = i2bf(sx4(b.w, 1));
    int c = (row >> 5) * 256 + (e8 >> 1) * 64 + (e8 & 1) * 32 + (row & 31);
    *(u16x8*)((char*)wsB + (size_t)(i >> 10) * HT_BYTES + c * 16) = r;
  }
}

// ---------------- 8-phase 256x256 GEMM, 32x32x16, pipelined loads ----------------
__global__ __launch_bounds__(512, 2)
void qgemm8(const unsigned short* __restrict__ wsA, const unsigned short* __restrict__ wsB,
            const float* __restrict__ scales, const float* __restrict__ bias,
            float* __restrict__ out) {
  __shared__ __align__(16) char smem[131072];  // 2 buf x (A 32KB + B 32KB)

  const int tid  = threadIdx.x;
  const int lane = tid & 63, wid = tid >> 6;
  const int wr = wid >> 2, wc = wid & 3;       // 2x4 wave grid; per-wave 128x64
  const int l31 = lane & 31, kg = lane >> 5;

  int bid = blockIdx.x;
  int id  = (bid & 7) * (NBLK2 / 8) + (bid >> 3);   // bijective XCD chunking
  int tm  = id & (NTM2 - 1), tn = id >> 4;          // tn-major: B panel shared per XCD

  const char* gA = (const char*)wsA + (size_t)tm * (NKT * 2) * HT_BYTES;
  const char* gB = (const char*)wsB + (size_t)tn * (NKT * 2) * HT_BYTES;

  // Per-lane fragment bases: read group = 64 lanes x 16B contiguous (conflict-free)
  const char* baseA = smem + wr * HT_BYTES + lane * 16;
  const char* baseB = smem + 32768 + (wc >> 1) * HT_BYTES + lane * 16;

#define STAGE(ldsoff, src) do { \
    async_copy16(smem + (ldsoff) + (wid * 64) * 16, (src) + (wid * 64 + lane) * 16); \
    async_copy16(smem + (ldsoff) + (512 + wid * 64) * 16, (src) + (512 + wid * 64 + lane) * 16); \
  } while (0)
#define STAGE_A(buf, h, kt) STAGE((buf) * 65536 + (h) * HT_BYTES, gA + ((kt) * 2 + (h)) * HT_BYTES)
#define STAGE_B(buf, h, kt) STAGE((buf) * 65536 + 32768 + (h) * HT_BYTES, gB + ((kt) * 2 + (h)) * HT_BYTES)

  f32x16 acc[4][2] = {};   // [msub 0..3][nsub 0..1], 128 regs
  bf16x8 aS0[2][4], aS1[2][4];   // A frag sets: [msub-in-pair][kstep]
  bf16x8 bS0[4], bS1[4];         // B frag sets: [kstep]

#define LDA_SET(dst, buf, sel) do { \
    _Pragma("unroll") for (int i = 0; i < 2; ++i) \
    _Pragma("unroll") for (int ks = 0; ks < 4; ++ks) \
      dst[i][ks] = *(const bf16x8*)(baseA + (buf) * 65536 + ((sel) * 2 + i) * 4096 + ks * 1024); \
  } while (0)
#define LDB_SET(dst, buf, bn) do { \
    _Pragma("unroll") for (int ks = 0; ks < 4; ++ks) \
      dst[ks] = *(const bf16x8*)(baseB + (buf) * 65536 + ((wc & 1) * 2 + (bn)) * 4096 + ks * 1024); \
  } while (0)
#define MMQ(aS, bS, sel, bn) do { \
    _Pragma("unroll") for (int ks = 0; ks < 4; ++ks) \
    _Pragma("unroll") for (int i = 0; i < 2; ++i) \
      acc[(sel) * 2 + i][bn] = __builtin_amdgcn_mfma_f32_32x32x16_bf16( \
          aS[i][ks], bS[ks], acc[(sel) * 2 + i][bn], 0, 0, 0); \
  } while (0)

#define PH_BAR __builtin_amdgcn_s_barrier()
#define LGKM0 asm volatile("s_waitcnt lgkmcnt(0)" ::: "memory")
#define VMC2  asm volatile("s_waitcnt vmcnt(2)" ::: "memory")
#define VMC4  asm volatile("s_waitcnt vmcnt(4)" ::: "memory")
#define PRIO1 __builtin_amdgcn_s_setprio(1)
#define PRIO0 __builtin_amdgcn_s_setprio(0)

  // Prologue: buf0 <- tile0 (8 loads), buf1.B <- tile1 (4 loads).
  STAGE_B(0, 0, 0); STAGE_B(0, 1, 0);
  STAGE_A(0, 0, 0); STAGE_A(0, 1, 0);
  STAGE_B(1, 0, 1); STAGE_B(1, 1, 1);
  VMC4;        // drain buf0's 8, keep buf1.B's 4 in flight
  PH_BAR;
  LDA_SET(aS0, 0, 0); LDB_SET(bS0, 0, 0);   // operands for ph0

  for (int t = 0; t < NKT / 2; ++t) {
    const int k1 = 2 * t + 1;
    const int k2 = (2 * t + 2 < NKT) ? 2 * t + 2 : NKT - 1;  // tail clamp (never read)
    const int k3 = (2 * t + 3 < NKT) ? 2 * t + 3 : NKT - 1;

    // ph0: Q(A0,B0)@buf0 ; prefetch bS1
    LGKM0; PRIO1; MMQ(aS0, bS0, 0, 0); PRIO0;
    STAGE_A(1, 0, k1);
    LDB_SET(bS1, 0, 1);
    PH_BAR;
    // ph1: Q(A0,B1) ; prefetch aS1
    LGKM0; PRIO1; MMQ(aS0, bS1, 0, 1); PRIO0;
    STAGE_A(1, 1, k1);
    LDA_SET(aS1, 0, 1);
    PH_BAR;
    // ph2: Q(A1,B1) ; drain buf1.A(k1)+buf1.B(k1)
    LGKM0; PRIO1; MMQ(aS1, bS1, 1, 1); PRIO0;
    STAGE_B(0, 0, k2);
    VMC2;
    PH_BAR;
    // ph3: Q(A1,B0) ; prefetch buf1 operands (aS0, bS0)
    PRIO1; MMQ(aS1, bS0, 1, 0); PRIO0;
    STAGE_B(0, 1, k2);
    LDA_SET(aS0, 1, 0); LDB_SET(bS0, 1, 0);
    PH_BAR;
    // ph4: Q(A0,B0)@buf1
    LGKM0; PRIO1; MMQ(aS0, bS0, 0, 0); PRIO0;
    STAGE_A(0, 0, k2);
    LDB_SET(bS1, 1, 1);
    PH_BAR;
    // ph5: Q(A0,B1)
    LGKM0; PRIO1; MMQ(aS0, bS1, 0, 1); PRIO0;
    STAGE_A(0, 1, k2);
    LDA_SET(aS1, 1, 1);
    PH_BAR;
    // ph6: Q(A1,B1) ; drain buf0.B(k2)+buf0.A(k2)
    LGKM0; PRIO1; MMQ(aS1, bS1, 1, 1); PRIO0;
    STAGE_B(1, 0, k3);
    VMC2;
    PH_BAR;
    // ph7: Q(A1,B0) ; prefetch buf0 operands for next iter
    PRIO1; MMQ(aS1, bS0, 1, 0); PRIO0;
    STAGE_B(1, 1, k3);
    LDA_SET(aS0, 0, 0); LDB_SET(bS0, 0, 0);
    PH_BAR;
  }

  // ---- epilogue: y = acc*scale + bias ----
  // 32x32 C/D (m74/m101): col = lane&31, row = (reg&3) + 8*(reg>>2) + 4*(lane>>5)
  const int m0 = tm * 256, n0 = tn * 256;
#pragma unroll
  for (int ni = 0; ni < 2; ++ni) {
    const int o = n0 + wc * 64 + ni * 32 + l31;
    const float s = scales[o];
    const float b = bias[o];
#pragma unroll
    for (int mi = 0; mi < 4; ++mi) {
      const int mrb = m0 + wr * 128 + mi * 32 + kg * 4;
#pragma unroll
      for (int r = 0; r < 16; ++r) {
        const int mr = mrb + (r & 3) + 8 * (r >> 2);
        __builtin_nontemporal_store(acc[mi][ni][r] * s + b,
                                    out + (size_t)mr * N_DIM + o);
      }
    }
  }
#undef STAGE
#undef STAGE_A
#undef STAGE_B
#undef LDA_SET
#undef LDB_SET
#undef MMQ
#undef PH_BAR
#undef LGKM0
#undef VMC2
#undef VMC4
#undef PRIO1
#undef PRIO0
}

// ---------------- fallback pre-pass (linear xb) + 128x128 GEMM ----------------
__global__ __launch_bounds__(256) void cvt_x_kernel(const float* __restrict__ x,
                                                    unsigned short* __restrict__ xb) {
  const int n4 = M_DIM * K_DIM / 4;
  int i = blockIdx.x * blockDim.x + threadIdx.x;
  const int stride = gridDim.x * blockDim.x;
  for (; i < n4; i += stride) {
    float4 v = ((const float4*)x)[i];
    ushort4 r;
    r.x = f2bf_rne(v.x); r.y = f2bf_rne(v.y);
    r.z = f2bf_rne(v.z); r.w = f2bf_rne(v.w);
    ((ushort4*)xb)[i] = r;
  }
}

template <int MODE>
__global__ __launch_bounds__(256)
void qgemm_kernel(const float* __restrict__ x, const unsigned short* __restrict__ xb,
                  const int* __restrict__ wp,
                  const float* __restrict__ scales, const float* __restrict__ bias,
                  float* __restrict__ out) {
  __shared__ __align__(16) unsigned short As[BM * BK];
  __shared__ __align__(16) unsigned short Bs[BN * BK];
  const int tid  = threadIdx.x;
  const int lane = tid & 63;
  const int wid  = tid >> 6;
  int bid = blockIdx.x;
  int swzb = (bid & 7) * (NBLK / 8) + (bid >> 3);
  const int tm = swzb & (NTM - 1);
  const int tn = swzb >> 5;
  const int m0 = tm * BM, n0 = tn * BN;
  const int wr = wid >> 1, wc = wid & 1;
  const int fr = lane & 15;
  const int fg = lane >> 4;
  f32x4 acc[4][4] = {};

  for (int kt = 0; kt < K_DIM / BK; ++kt) {
    int4   breg[4];
    float4 areg[8];
#pragma unroll
    for (int p = 0; p < 4; ++p) {
      int fl = p * 256 + tid;
      int row = fl >> 3, u = fl & 7;
      breg[p] = *(const int4*)(wp + (size_t)(n0 + row) * KP + kt * (BK / 2) + u * 4);
    }
    if constexpr (MODE == 2) {
#pragma unroll
      for (int p = 0; p < 8; ++p) {
        int fl = p * 256 + tid;
        int row = fl >> 4, u = fl & 15;
        areg[p] = *(const float4*)(x + (size_t)(m0 + row) * K_DIM + kt * BK + u * 4);
      }
    }
    __syncthreads();
    if constexpr (MODE == 1) {
#pragma unroll
      for (int p = 0; p < 4; ++p) {
        int t16 = p * 256 + tid;
        int row = t16 >> 3, u = t16 & 7;
        const unsigned short* g = xb + (size_t)(m0 + row) * K_DIM + kt * BK + u * 8;
        async_copy16((char*)As + (p * 256 + wid * 64) * 16, g);
      }
    } else {
#pragma unroll
      for (int p = 0; p < 8; ++p) {
        int fl = p * 256 + tid;
        int row = fl >> 4, u = fl & 15;
        ushort4 r;
        r.x = f2bf_rne(areg[p].x); r.y = f2bf_rne(areg[p].y);
        r.z = f2bf_rne(areg[p].z); r.w = f2bf_rne(areg[p].w);
        *(ushort4*)((char*)As + row * 128 + u * 8) = r;
      }
    }
#pragma unroll
    for (int p = 0; p < 4; ++p) {
      int fl = p * 256 + tid;
      int row = fl >> 3, u = fl & 7;
      int4 b = breg[p];
      u16x8 r;
      r[0] = i2bf(sx4(b.x, 0)); r[1] = i2bf(sx4(b.x, 1));
      r[2] = i2bf(sx4(b.y, 0)); r[3] = i2bf(sx4(b.y, 1));
      r[4] = i2bf(sx4(b.z, 0)); r[5] = i2bf(sx4(b.z, 1));
      r[6] = i2bf(sx4(b.w, 0)); r[7] = i2bf(sx4(b.w, 1));
      *(u16x8*)((char*)Bs + row * 128 + u * 16) = r;
    }
    __syncthreads();
#pragma unroll
    for (int kk = 0; kk < 2; ++kk) {
      const int kb = kk * 64 + fg * 16;
      bf16x8 af[4], bfv[4];
#pragma unroll
      for (int mi = 0; mi < 4; ++mi) {
        int row = wr * 64 + mi * 16 + fr;
        af[mi] = *(const bf16x8*)((const char*)As + row * 128 + kb);
      }
#pragma unroll
      for (int ni = 0; ni < 4; ++ni) {
        int row = wc * 64 + ni * 16 + fr;
        bfv[ni] = *(const bf16x8*)((const char*)Bs + row * 128 + kb);
      }
#pragma unroll
      for (int mi = 0; mi < 4; ++mi)
#pragma unroll
        for (int ni = 0; ni < 4; ++ni)
          acc[mi][ni] = __builtin_amdgcn_mfma_f32_16x16x32_bf16(af[mi], bfv[ni], acc[mi][ni], 0, 0, 0);
    }
  }
#pragma unroll
  for (int ni = 0; ni < 4; ++ni) {
    const int o = n0 + wc * 64 + ni * 16 + fr;
    const float s = scales[o];
    const float b = bias[o];
#pragma unroll
    for (int mi = 0; mi < 4; ++mi) {
      const int mr = m0 + wr * 64 + mi * 16 + fg * 4;
#pragma unroll
      for (int r = 0; r < 4; ++r)
        out[(size_t)(mr + r) * N_DIM + o] = acc[mi][ni][r] * s + b;
    }
  }
}

extern "C" void kernel_launch(void* const* d_in, const int* in_sizes, int n_in,
                              void* d_out, int out_size, void* d_ws, size_t ws_size,
                              hipStream_t stream) {
  const float* x  = (const float*)d_in[0];
  const int*   wp = (const int*)d_in[1];
  const float* sc = (const float*)d_in[2];
  const float* bs = (const float*)d_in[3];
  float* out = (float*)d_out;

  const size_t a_bytes = (size_t)NTM2 * NKT * 2 * HT_BYTES;  // 33,554,432
  const size_t b_bytes = (size_t)NTN2 * NKT * 2 * HT_BYTES;  // 90,177,536
  unsigned short* wsA = (unsigned short*)d_ws;
  unsigned short* wsB = (unsigned short*)((char*)d_ws + a_bytes);

  if (ws_size >= a_bytes + b_bytes) {
    cvt_x_tiled<<<2048, 256, 0, stream>>>(x, wsA);
    deq_w_tiled<<<2048, 256, 0, stream>>>(wp, wsB);
    qgemm8<<<NBLK2, 512, 0, stream>>>(wsA, wsB, sc, bs, out);
  } else if (ws_size >= a_bytes) {
    cvt_x_kernel<<<2048, 256, 0, stream>>>(x, wsA);
    qgemm_kernel<1><<<NBLK, 256, 0, stream>>>(x, wsA, wp, sc, bs, out);
  } else {
    qgemm_kernel<2><<<NBLK, 256, 0, stream>>>(x, wsA, wp, sc, bs, out);
  }
}